// Round 13
// baseline (267.959 us; speedup 1.0000x reference)
//
#include <hip/hip_runtime.h>
#include <hip/hip_bf16.h>
#include <stdint.h>

typedef unsigned short u16;
typedef short short8 __attribute__((ext_vector_type(8)));
typedef float floatx4 __attribute__((ext_vector_type(4)));

#define S_LEN 2048
#define NB 2
#define NH 8
#define R_TOK (NB * S_LEN)  // 4096

#define L2_THETA 13.287712379549449f
// attention scale folded into Q, log2 domain: (1/sqrt(128)) * log2(e)
#define QSCALE (0.08838834764831845f * 1.4426950408889634f)

__device__ inline u16 f2bf(float f) {
  union { float f; uint32_t u; } x; x.f = f;
  uint32_t r = (x.u + 0x7fffu + ((x.u >> 16) & 1u)) >> 16;
  return (u16)r;
}
__device__ inline float bf2f(u16 h) {
  union { uint32_t u; float f; } x; x.u = ((uint32_t)h) << 16;
  return x.f;
}
__device__ inline floatx4 mfma16(short8 a, short8 b, floatx4 c) {
  return __builtin_amdgcn_mfma_f32_16x16x32_bf16(a, b, c, 0, 0, 0);
}
__device__ inline uint32_t pkbf(float a, float b) {
  union { __hip_bfloat162 h; uint32_t u; } c;
  c.h = __float22bfloat162_rn(make_float2(a, b));
  return c.u;
}
__device__ __forceinline__ void cp16(const void* g, const void* l) {
  __builtin_amdgcn_global_load_lds(
      (const __attribute__((address_space(1))) uint32_t*)(uintptr_t)g,
      (__attribute__((address_space(3))) uint32_t*)(uintptr_t)l, 16, 0, 0);
}

// ---------------- prep part 1 (r13): waT transpose + biasA only ----------------
// x->bf16 conversion pass ELIMINATED: gemm-A now reads x fp32 directly with in-register
// f2bf (bitwise-identical). 321 blocks.
__global__ __launch_bounds__(256) void k_prep1(
    const float* __restrict__ wdq, const float* __restrict__ wdkv, u16* __restrict__ waT,
    const float* __restrict__ bdq, const float* __restrict__ bdkv,
    float* __restrict__ biasA) {
  __shared__ u16 tile[32][33];
  const int s = blockIdx.x, tid = threadIdx.x;
  const int tx = tid & 31, ty = tid >> 5;
  if (s < 320) {  // waT: logical [1024][320] -> [320][1024]
    int bx = s % 10, by = s / 10;
    int c0 = bx * 32, r0 = by * 32;
#pragma unroll
    for (int i = 0; i < 4; ++i) {
      int r = r0 + ty + i * 8, c = c0 + tx;
      float v = (c < 128) ? wdq[(size_t)r * 128 + c] : wdkv[(size_t)r * 192 + (c - 128)];
      tile[ty + i * 8][tx] = f2bf(v);
    }
    __syncthreads();
#pragma unroll
    for (int i = 0; i < 4; ++i)
      waT[(size_t)(c0 + ty + i * 8) * 1024 + r0 + tx] = tile[tx][ty + i * 8];
  } else {
    if (tid < 320) biasA[tid] = (tid < 128) ? bdq[tid] : bdkv[tid - 128];
  }
}

// ------- gemm-A + weight-transpose uber-kernel (r13) -------
// blockIdx < 96: gemm path, A = x fp32 read directly, reg-staged with in-register f2bf
// (T14: loads issued post-barrier, converted+written post-compute -> HBM latency hides
// under the 16-MFMA step). B = waT via global_load_lds (unchanged). Removes the 50MB
// x->bf16 serial pass. Else: 32x32 weight transposes (k_prep-exact bodies) fill the
// 160 CUs gemm-A leaves idle.
__global__ __launch_bounds__(256) void k_gemma_wt(
    const float* __restrict__ xf, const u16* __restrict__ BT,
    const float* __restrict__ bias, float* __restrict__ Cout,
    const float* __restrict__ wuq, u16* __restrict__ wQT,
    const float* __restrict__ wukv, u16* __restrict__ wKVT,
    const float* __restrict__ wo, u16* __restrict__ wOT) {
  const int tid = threadIdx.x;
  if (blockIdx.x >= 96) {  // ---- transpose path (block-uniform) ----
    __shared__ u16 tile[32][33];
    int t = blockIdx.x - 96;
    const float* in; u16* out; int R, C, bx, by;
    if (t < 128) { in = wuq; out = wQT; R = 128; C = 1024; bx = t & 31; by = t >> 5; }
    else if (t < 448) { int u = t - 128; in = wukv; out = wKVT; R = 128; C = 2560; bx = u % 80; by = u / 80; }
    else { int u = t - 448; in = wo; out = wOT; R = 2048; C = 1024; bx = u & 31; by = u >> 5; }
    const int tx = tid & 31, ty = tid >> 5;
    int c0 = bx * 32, r0 = by * 32;
#pragma unroll
    for (int i = 0; i < 4; ++i)
      tile[ty + i * 8][tx] = f2bf(in[(size_t)(r0 + ty + i * 8) * C + c0 + tx]);
    __syncthreads();
#pragma unroll
    for (int i = 0; i < 4; ++i)
      out[(size_t)(c0 + ty + i * 8) * R + r0 + tx] = tile[tx][ty + i * 8];
    return;
  }
  // ---- gemm path: M=4096, N=320, K=1024, fp32 out; A from x fp32 ----
  const int N = 320, K = 1024;
  __shared__ __align__(16) u16 Alds[2][128 * 32];
  __shared__ __align__(16) u16 Blds[2][128 * 32];
  const int wave = tid >> 6, lane = tid & 63;
  const int lane15 = lane & 15, quad = lane >> 4;
  const int n0 = (blockIdx.x % 3) * 128, m0 = (blockIdx.x / 3) * 128;
  const int mw = (wave & 1) * 64, nw = (wave >> 1) * 64;

  floatx4 acc[4][4];
#pragma unroll
  for (int a = 0; a < 4; ++a)
#pragma unroll
    for (int b = 0; b < 4; ++b) acc[a][b] = (floatx4){0.f, 0.f, 0.f, 0.f};

  // A staging (reg-staged fp32): 256 thr x 16 floats = 128 rows x 32 cols
  const int arow = tid >> 1, acol = (tid & 1) * 16;
  const float* agp = xf + (size_t)(m0 + arow) * K + acol;
  float4 areg[4];
  auto loadA = [&](int k0) {
#pragma unroll
    for (int i = 0; i < 4; ++i) areg[i] = *(const float4*)(agp + k0 + i * 4);
  };
  auto writeA = [&](int buf) {
#pragma unroll
    for (int i = 0; i < 4; ++i) {
      ushort4 w;
      w.x = f2bf(areg[i].x); w.y = f2bf(areg[i].y);
      w.z = f2bf(areg[i].z); w.w = f2bf(areg[i].w);
      *(ushort4*)&Alds[buf][arow * 32 + acol + i * 4] = w;
    }
  };
  // B staging (async, unchanged)
  const int srow = wave * 32 + (lane >> 2);
  const int scol = (lane & 3) * 8;
  auto issueB = [&](int k0, int buf) {
    const u16* gb = BT + (size_t)(n0 + srow) * K + k0 + scol;
    cp16(gb, Blds[buf] + srow * 32 + scol);
    cp16(gb + (size_t)16 * K, Blds[buf] + (srow + 16) * 32 + scol);
  };

  // prologue: fill buf0 (A via regs, B async)
  loadA(0);
  issueB(0, 0);
  writeA(0);
  int cur = 0;
  for (int k0 = 0; k0 < K; k0 += 32) {
    __syncthreads();  // drains A ds_writes (lgkm) + B cp16 (vmcnt): buf[cur] ready
    if (k0 + 32 < K) {
      loadA(k0 + 32);        // fp32 loads in flight across compute
      issueB(k0 + 32, cur ^ 1);
    }
    short8 af[4], bf[4];
#pragma unroll
    for (int im = 0; im < 4; ++im)
      af[im] = *(const short8*)&Alds[cur][(mw + im * 16 + lane15) * 32 + quad * 8];
#pragma unroll
    for (int in = 0; in < 4; ++in)
      bf[in] = *(const short8*)&Blds[cur][(nw + in * 16 + lane15) * 32 + quad * 8];
#pragma unroll
    for (int im = 0; im < 4; ++im)
#pragma unroll
      for (int in = 0; in < 4; ++in) acc[im][in] = mfma16(af[im], bf[in], acc[im][in]);
    if (k0 + 32 < K) writeA(cur ^ 1);  // loads landed during compute; buf^1 readers
                                       // were sealed by this iteration's barrier
    cur ^= 1;
  }

#pragma unroll
  for (int im = 0; im < 4; ++im)
#pragma unroll
    for (int in = 0; in < 4; ++in)
#pragma unroll
      for (int r = 0; r < 4; ++r) {
        int row = m0 + mw + im * 16 + quad * 4 + r;
        int col = n0 + nw + in * 16 + lane15;
        if (col < N) Cout[(size_t)row * N + col] = acc[im][in][r] + bias[col];
      }
}

// ---------------- 128x128-tile GEMM, B transposed [N][K], double-buffered async ----------
template <int OUT_BF>
__global__ __launch_bounds__(256) void k_gemm_bt(const u16* __restrict__ A,
                                                 const u16* __restrict__ BT,
                                                 const float* __restrict__ bias,
                                                 void* __restrict__ Cout,
                                                 int M, int N, int K) {
  __shared__ __align__(16) u16 Alds[2][128 * 32];
  __shared__ __align__(16) u16 Blds[2][128 * 32];
  const int tid = threadIdx.x;
  const int wave = tid >> 6, lane = tid & 63;
  const int lane15 = lane & 15, quad = lane >> 4;
  const int m0 = blockIdx.y * 128, n0 = blockIdx.x * 128;
  const int mw = (wave & 1) * 64, nw = (wave >> 1) * 64;

  floatx4 acc[4][4];
#pragma unroll
  for (int a = 0; a < 4; ++a)
#pragma unroll
    for (int b = 0; b < 4; ++b) acc[a][b] = (floatx4){0.f, 0.f, 0.f, 0.f};

  const int srow = wave * 32 + (lane >> 2);
  const int scol = (lane & 3) * 8;

  auto stage = [&](int k0, int buf) {
    const u16* ga = A + (size_t)(m0 + srow) * K + k0 + scol;
    cp16(ga, Alds[buf] + srow * 32 + scol);
    cp16(ga + (size_t)16 * K, Alds[buf] + (srow + 16) * 32 + scol);
    const u16* gb = BT + (size_t)(n0 + srow) * K + k0 + scol;
    cp16(gb, Blds[buf] + srow * 32 + scol);
    cp16(gb + (size_t)16 * K, Blds[buf] + (srow + 16) * 32 + scol);
  };

  stage(0, 0);
  int cur = 0;
  for (int k0 = 0; k0 < K; k0 += 32) {
    __syncthreads();
    if (k0 + 32 < K) stage(k0 + 32, cur ^ 1);
    short8 af[4], bf[4];
#pragma unroll
    for (int im = 0; im < 4; ++im)
      af[im] = *(const short8*)&Alds[cur][(mw + im * 16 + lane15) * 32 + quad * 8];
#pragma unroll
    for (int in = 0; in < 4; ++in)
      bf[in] = *(const short8*)&Blds[cur][(nw + in * 16 + lane15) * 32 + quad * 8];
#pragma unroll
    for (int im = 0; im < 4; ++im)
#pragma unroll
      for (int in = 0; in < 4; ++in) acc[im][in] = mfma16(af[im], bf[in], acc[im][in]);
    cur ^= 1;
  }

#pragma unroll
  for (int im = 0; im < 4; ++im)
#pragma unroll
    for (int in = 0; in < 4; ++in)
#pragma unroll
      for (int r = 0; r < 4; ++r) {
        int row = m0 + mw + im * 16 + quad * 4 + r;
        int col = n0 + nw + in * 16 + lane15;
        if (col < N) {
          float v = acc[im][in][r] + bias[col];
          if (OUT_BF)
            ((u16*)Cout)[(size_t)row * N + col] = f2bf(v);
          else
            ((float*)Cout)[(size_t)row * N + col] = v;
        }
      }
}

// ------- fused Q+KV GEMM uber-kernel (r10) -------
__global__ __launch_bounds__(256) void k_gemm_qkv(
    const u16* __restrict__ Aq, const u16* __restrict__ BTq,
    const float* __restrict__ biasq, const float* __restrict__ qtab,
    u16* __restrict__ qstates,
    const u16* __restrict__ Akv, const u16* __restrict__ BTkv,
    const float* __restrict__ biaskv, u16* __restrict__ kvb, u16* __restrict__ vT) {
  const int K = 128;
  __shared__ __align__(16) u16 Alds[2][128 * 32];
  __shared__ __align__(16) u16 Blds[2][128 * 32];
  __shared__ __align__(16) u16 eplds[64 * 136];  // kv V-epilogue staging, 17.4 KB
  const int tid = threadIdx.x;
  const int wave = tid >> 6, lane = tid & 63;
  const int lane15 = lane & 15, quad = lane >> 4;
  const bool isq = blockIdx.x < 256;
  int m0, n0;
  const u16 *A, *BT;
  if (isq) {  // q: grid (32 m) x (8 n), m fastest
    int qb = blockIdx.x;
    m0 = (qb & 31) * 128;
    n0 = (qb >> 5) * 128;
    A = Aq; BT = BTq;
  } else {    // kv: grid (20 n) x (32 m), n fastest
    int kb = blockIdx.x - 256;
    n0 = (kb % 20) * 128;
    m0 = (kb / 20) * 128;
    A = Akv; BT = BTkv;
  }
  const int mw = (wave & 1) * 64, nw = (wave >> 1) * 64;

  floatx4 acc[4][4];
#pragma unroll
  for (int a = 0; a < 4; ++a)
#pragma unroll
    for (int b = 0; b < 4; ++b) acc[a][b] = (floatx4){0.f, 0.f, 0.f, 0.f};

  const int srow = wave * 32 + (lane >> 2);
  const int scol = (lane & 3) * 8;
  auto stage = [&](int k0, int buf) {
    const u16* ga = A + (size_t)(m0 + srow) * K + k0 + scol;
    cp16(ga, Alds[buf] + srow * 32 + scol);
    cp16(ga + (size_t)16 * K, Alds[buf] + (srow + 16) * 32 + scol);
    const u16* gb = BT + (size_t)(n0 + srow) * K + k0 + scol;
    cp16(gb, Blds[buf] + srow * 32 + scol);
    cp16(gb + (size_t)16 * K, Blds[buf] + (srow + 16) * 32 + scol);
  };

  stage(0, 0);
  int cur = 0;
  for (int k0 = 0; k0 < K; k0 += 32) {
    __syncthreads();
    if (k0 + 32 < K) stage(k0 + 32, cur ^ 1);
    short8 af[4], bf[4];
#pragma unroll
    for (int im = 0; im < 4; ++im)
      af[im] = *(const short8*)&Alds[cur][(mw + im * 16 + lane15) * 32 + quad * 8];
#pragma unroll
    for (int in = 0; in < 4; ++in)
      bf[in] = *(const short8*)&Blds[cur][(nw + in * 16 + lane15) * 32 + quad * 8];
#pragma unroll
    for (int im = 0; im < 4; ++im)
#pragma unroll
      for (int in = 0; in < 4; ++in) acc[im][in] = mfma16(af[im], bf[in], acc[im][in]);
    cur ^= 1;
  }

  if (isq) {  // ---- q epilogue: rope(table) + scale + scatter (r8-exact) ----
    const bool ropeblk = (n0 >= 768);
#pragma unroll
    for (int in = 0; in < 4; ++in) {
      const int col = n0 + nw + in * 16 + lane15;
#pragma unroll
      for (int im = 0; im < 4; ++im) {
        if (!ropeblk) {
          const int h = col / 96, d = col - h * 96;
#pragma unroll
          for (int r = 0; r < 4; ++r) {
            int row = m0 + mw + im * 16 + quad * 4 + r;
            int b = row >> 11, s = row & (S_LEN - 1);
            float v = acc[im][in][r] + biasq[col];
            qstates[((size_t)(b * NH + h) * S_LEN + s) * 128 + d] = f2bf(v * QSCALE);
          }
        } else {
          const int j = (col - 768) & 31, h = (col - 768) >> 5, pr = j >> 1;
#pragma unroll
          for (int r = 0; r < 4; ++r) {
            int row = m0 + mw + im * 16 + quad * 4 + r;
            int b = row >> 11, s = row & (S_LEN - 1);
            float v = acc[im][in][r] + biasq[col];
            float vp = __shfl_xor(v, 1);  // partner col^1 = lane15^1, same row
            float xe = (lane & 1) ? vp : v;
            float xo = (lane & 1) ? v : vp;
            float2 cs = *(const float2*)&qtab[((size_t)row * 16 + pr) * 2];  // (cos, sin)
            float val = (j & 1) ? (xe * cs.y + xo * cs.x) : (xe * cs.x - xo * cs.y);
            qstates[((size_t)(b * NH + h) * S_LEN + s) * 128 + 96 + j] = f2bf(val * QSCALE);
          }
        }
      }
    }
  } else if (n0 < 512) {  // ---- kv k_nope epilogue (r8-exact) ----
#pragma unroll
    for (int im = 0; im < 4; ++im)
#pragma unroll
      for (int in = 0; in < 4; ++in)
#pragma unroll
        for (int r = 0; r < 4; ++r) {
          int row = m0 + mw + im * 16 + quad * 4 + r;
          int col = n0 + nw + in * 16 + lane15;
          kvb[(size_t)row * 2560 + col] = f2bf(acc[im][in][r] + biaskv[col]);
        }
  } else {  // ---- kv V epilogue: two-pass LDS-staged coalesced vT write (r8-exact) ----
    const int sbase = m0 & (S_LEN - 1), bq = m0 >> 11;
#pragma unroll
    for (int hh = 0; hh < 2; ++hh) {
#pragma unroll
      for (int im = 0; im < 4; ++im) {
        const int rrel = mw + im * 16 + quad * 4;  // block-relative s, 0..127
        const int bb = (rrel & 63) >> 2;
        const int a = (bb & 8) | (((bb >> 1) & 1) << 2) | ((bb & 1) << 1) | ((bb >> 2) & 1);
        const int prel = (rrel >> 6) * 64 + a * 4;
#pragma unroll
        for (int ii = 0; ii < 2; ++ii) {
          const int in = hh * 2 + ii;
          const int nl = nw + in * 16 + lane15;
          const int slot = (nl & 31) | ((nl & 64) >> 1);
          const float bv = biaskv[n0 + nl];
          ushort4 o;
          o.x = f2bf(acc[im][in][0] + bv);
          o.y = f2bf(acc[im][in][1] + bv);
          o.z = f2bf(acc[im][in][2] + bv);
          o.w = f2bf(acc[im][in][3] + bv);
          *(ushort4*)&eplds[slot * 136 + prel] = o;
        }
      }
      __syncthreads();
#pragma unroll
      for (int i = 0; i < 4; ++i) {
        int idx = i * 256 + tid;
        int slot = idx >> 4, c8 = (idx & 15) * 8;
        int nl = (slot & 31) + hh * 32 + ((slot & 32) << 1);
        int c2 = n0 + nl - 512;
        int hv = c2 >> 8, nn = c2 & 255;
        short8 v = *(const short8*)&eplds[slot * 136 + c8];
        *(short8*)&vT[((size_t)((bq * NH + hv) * 256 + nn)) * 2048 + sbase + c8] = v;
      }
      if (hh == 0) __syncthreads();
    }
  }
}

// ------- stage-A epilogue: rmsnorm(cq), rmsnorm(ckv), rope(k_rope), q-rope table -------
__global__ void k_stagea(const float* __restrict__ t0, const float* __restrict__ qnw,
                         const float* __restrict__ kvnw, const int* __restrict__ pos_ids,
                         u16* __restrict__ cq, u16* __restrict__ ckv,
                         u16* __restrict__ krope, float* __restrict__ qtab) {
  int r = blockIdx.x, tid = threadIdx.x;  // 128 threads
  const float* row = t0 + (size_t)r * 320;
  float a = row[tid];
  float b = row[128 + tid];
  float sa = a * a, sb = b * b;
#pragma unroll
  for (int d = 1; d < 64; d <<= 1) {
    sa += __shfl_xor(sa, d);
    sb += __shfl_xor(sb, d);
  }
  __shared__ float red[4];
  if ((tid & 63) == 0) { red[(tid >> 6) * 2] = sa; red[(tid >> 6) * 2 + 1] = sb; }
  __syncthreads();
  sa = red[0] + red[2];
  sb = red[1] + red[3];
  float ra = rsqrtf(sa * (1.0f / 128.0f) + 1e-8f);
  float rb = rsqrtf(sb * (1.0f / 128.0f) + 1e-8f);
  cq[(size_t)r * 128 + tid] = f2bf(qnw[tid] * a * ra);
  ckv[(size_t)r * 128 + tid] = f2bf(kvnw[tid] * b * rb);
  if (tid < 32) {
    float xe = row[256 + 2 * tid], xo = row[256 + 2 * tid + 1];
    float p = (float)pos_ids[r];
    float freq = exp2f(-(2.0f * tid / 64.0f) * L2_THETA);
    float ang = p * freq;
    float c = cosf(ang), s = sinf(ang);
    krope[(size_t)r * 64 + 2 * tid] = f2bf(xe * c - xo * s);
    krope[(size_t)r * 64 + 2 * tid + 1] = f2bf(xe * s + xo * c);
  } else if (tid < 48) {
    // q-rope table: bitwise-identical formula to the old k_stageb path
    int pr = tid - 32;
    float p = (float)pos_ids[r];
    float freq = exp2f(-(2.0f * pr / 32.0f) * L2_THETA);
    float ang = p * freq;
    qtab[((size_t)r * 16 + pr) * 2] = cosf(ang);
    qtab[((size_t)r * 16 + pr) * 2 + 1] = sinf(ang);
  }
}

// ---------------- flash attention: 2-phase double-buffered pipeline (r3-exact) ----------
// Best-known attn: 88.1-90us, reproduced 6x. All deviations regressed: r5 n-split (+26%),
// r9 q-split (+17%, 1 wave/SIMD), r11 V-frag hoist (+2.5us, VGPR 88->100 perturbed the
// compiler's schedule). This structure is the banked floor -- do not edit.
__global__ __launch_bounds__(512) void k_attn(const u16* __restrict__ qstates,
                                              const u16* __restrict__ kv,
                                              const u16* __restrict__ krope,
                                              const u16* __restrict__ vT,
                                              u16* __restrict__ attn_out) {
  const int pair = blockIdx.x;  // 0..15 (pair-major: XCD = pair%8)
  const int qblk = blockIdx.y;  // 0..15
  const int b = pair >> 3, h = pair & 7;
  const int tid = threadIdx.x;
  const int wave = tid >> 6, lane = tid & 63;
  const int lane15 = lane & 15, quad = lane >> 4;
  const int w4 = wave & 3, half = wave >> 2;

  __shared__ __align__(16) u16 Klds[2][64 * 128];   // 2 x 16 KB
  __shared__ __align__(16) u16 Vlds[2][256 * 64];   // 2 x 32 KB

  const int qrow0 = qblk * 128 + wave * 16;
  short8 qfrag[4];
  {
    const u16* qb = qstates + ((size_t)(b * NH + h) * S_LEN + qrow0 + lane15) * 128 + quad * 8;
#pragma unroll
    for (int c = 0; c < 4; ++c) qfrag[c] = *(const short8*)(qb + c * 32);
  }

  floatx4 o_acc[16];
#pragma unroll
  for (int g = 0; g < 16; ++g) o_acc[g] = (floatx4){0.f, 0.f, 0.f, 0.f};
  float m_i = -1e30f;
  float l_i = 0.f;  // per-lane PARTIAL row-sum; reduced at epilogue

  // ---- hoisted, ch-invariant LDS read offsets (u16 units) ----
  const int kbase = (quad * 16 + lane15) * 8;  // + (t*16+c*4)*128 (imm)
  int vo0[4], vo1[4];
#pragma unroll
  for (int ph = 0; ph < 4; ++ph) {
    int n = ph * 16 + lane15;
    int sw = (n ^ (n >> 3)) & 7;
    vo0[ph] = n * 64 + ((quad ^ sw) & 7) * 8;
    vo1[ph] = n * 64 + (((quad | 4) ^ sw) & 7) * 8;
  }

  // K staging (512 thr, 2 cp16/thread): row = w4*16+lane15, unit u = half*8 + 4j + quad.
  const u16* kp[2];
  int kstr[2];
  int kdst[2];
#pragma unroll
  for (int j = 0; j < 2; ++j) {
    int u = half * 8 + j * 4 + quad;
    const u16* base;
    int str;
    if (u < 8) { base = kv + h * 64 + u * 8; str = 2560; }
    else { base = krope + (u - 8) * 8; str = 64; }
    kp[j] = base + (size_t)(b * S_LEN + w4 * 16 + lane15) * str;
    kstr[j] = str;
    kdst[j] = (w4 * 256 + (half * 2 + j) * 64 + lane) * 8;
  }
  // V staging (512 thr, 4 cp16/thread): n = oi*64 + (tid>>3), slot = tid&7
  const int vn6 = tid >> 3, vsl = tid & 7;
  const u16* vp[4];
#pragma unroll
  for (int oi = 0; oi < 4; ++oi) {
    int n = oi * 64 + vn6;
    int u = vsl ^ ((n ^ (n >> 3)) & 7);
    vp[oi] = vT + ((size_t)pair * 256 + n) * 2048 + u * 8;
  }

  auto issueK = [&](int buf) {
#pragma unroll
    for (int j = 0; j < 2; ++j) {
      cp16(kp[j], &Klds[buf][kdst[j]]);
      kp[j] += (size_t)64 * kstr[j];
    }
  };
  auto issueV = [&](int buf) {
#pragma unroll
    for (int oi = 0; oi < 4; ++oi) {
      cp16(vp[oi], &Vlds[buf][(oi * 512 + tid) * 8]);
      vp[oi] += 64;
    }
  };

  // prologue: fill buf0, drain, converge
  issueK(0);
  issueV(0);
  asm volatile("s_waitcnt vmcnt(0)" ::: "memory");
  __builtin_amdgcn_sched_barrier(0);
  __builtin_amdgcn_s_barrier();

  int cur = 0;
  for (int ch = 0; ch < S_LEN / 64; ++ch) {
    if (ch + 1 < S_LEN / 64) {
      issueK(cur ^ 1);
      issueV(cur ^ 1);
    }

    // S^T = K * Q^T : st[t][r] = S[q=lane15][k = t*16 + quad*4 + r] (log2 domain)
    floatx4 st[4];
#pragma unroll
    for (int t = 0; t < 4; ++t) st[t] = (floatx4){0.f, 0.f, 0.f, 0.f};
    __builtin_amdgcn_s_setprio(1);
#pragma unroll
    for (int c = 0; c < 4; ++c) {
      short8 qf = qfrag[c];
#pragma unroll
      for (int t = 0; t < 4; ++t) {
        short8 kf = *(const short8*)&Klds[cur][kbase + (t * 16 + c * 4) * 128];
        st[t] = mfma16(kf, qf, st[t]);
      }
    }
    __builtin_amdgcn_s_setprio(0);

    // row max: fmax tree + 2-shfl butterfly (l-sum reduce deferred to epilogue)
    float mloc = st[0][0];
#pragma unroll
    for (int t = 0; t < 4; ++t)
#pragma unroll
      for (int r = 0; r < 4; ++r) mloc = fmaxf(mloc, st[t][r]);
    mloc = fmaxf(mloc, __shfl_xor(mloc, 16));
    mloc = fmaxf(mloc, __shfl_xor(mloc, 32));

    // defer-max: only rescale when max grew by >8 (log2 domain); P bounded by 2^8
    const bool resc = __any(mloc > m_i + 8.0f);
    const float mref = resc ? fmaxf(m_i, mloc) : m_i;

    float rs = 0.f;
    union { short8 s; uint4 u; } a01, a23;
    {
      float p0, p1, p2, p3;
      p0 = exp2f(st[0][0] - mref); p1 = exp2f(st[0][1] - mref);
      p2 = exp2f(st[0][2] - mref); p3 = exp2f(st[0][3] - mref);
      rs += (p0 + p1) + (p2 + p3);
      a01.u.x = pkbf(p0, p1); a01.u.y = pkbf(p2, p3);
      p0 = exp2f(st[1][0] - mref); p1 = exp2f(st[1][1] - mref);
      p2 = exp2f(st[1][2] - mref); p3 = exp2f(st[1][3] - mref);
      rs += (p0 + p1) + (p2 + p3);
      a01.u.z = pkbf(p0, p1); a01.u.w = pkbf(p2, p3);
      p0 = exp2f(st[2][0] - mref); p1 = exp2f(st[2][1] - mref);
      p2 = exp2f(st[2][2] - mref); p3 = exp2f(st[2][3] - mref);
      rs += (p0 + p1) + (p2 + p3);
      a23.u.x = pkbf(p0, p1); a23.u.y = pkbf(p2, p3);
      p0 = exp2f(st[3][0] - mref); p1 = exp2f(st[3][1] - mref);
      p2 = exp2f(st[3][2] - mref); p3 = exp2f(st[3][3] - mref);
      rs += (p0 + p1) + (p2 + p3);
      a23.u.z = pkbf(p0, p1); a23.u.w = pkbf(p2, p3);
    }

    if (resc) {  // rare after chunk 0 (THR=8): alpha rescale of o_acc + l_i
      float alpha = exp2f(m_i - mref);
      m_i = mref;
      l_i = l_i * alpha + rs;
      float al[4];
#pragma unroll
      for (int r = 0; r < 4; ++r) al[r] = __shfl(alpha, quad * 4 + r, 16);
#pragma unroll
      for (int g = 0; g < 16; ++g) {
        o_acc[g][0] *= al[0]; o_acc[g][1] *= al[1];
        o_acc[g][2] *= al[2]; o_acc[g][3] *= al[3];
      }
    } else {
      l_i += rs;
    }

    // PV: b-frags are single b128 reads (permuted-k vT layout, hoisted bases)
    __builtin_amdgcn_s_setprio(1);
#pragma unroll
    for (int g = 0; g < 16; ++g) {
      short8 b01 = *(const short8*)&Vlds[cur][vo0[g & 3] + (g >> 2) * 4096];
      short8 b23 = *(const short8*)&Vlds[cur][vo1[g & 3] + (g >> 2) * 4096];
      floatx4 o = o_acc[g];
      o = mfma16(a01.s, b01, o);
      o = mfma16(a23.s, b23, o);
      o_acc[g] = o;
    }
    __builtin_amdgcn_s_setprio(0);

    // single per-chunk sync: next-chunk loads had all of compute to land;
    // barrier seals this chunk's LDS reads before buf[cur] is overwritten.
    asm volatile("s_waitcnt vmcnt(0)" ::: "memory");
    __builtin_amdgcn_sched_barrier(0);
    __builtin_amdgcn_s_barrier();
    cur ^= 1;
  }

  // epilogue: reduce the per-quad partial row-sums once, then normalize
  float lsum = l_i;
  lsum += __shfl_xor(lsum, 16);
  lsum += __shfl_xor(lsum, 32);
  float rl = 1.0f / lsum;
  float linv[4];
#pragma unroll
  for (int r = 0; r < 4; ++r) linv[r] = __shfl(rl, quad * 4 + r, 16);
#pragma unroll
  for (int g = 0; g < 16; ++g) {
#pragma unroll
    for (int r = 0; r < 4; ++r) {
      int row = qrow0 + quad * 4 + r;
      int col = h * 256 + g * 16 + lane15;
      attn_out[((size_t)b * S_LEN + row) * 2048 + col] = f2bf(o_acc[g][r] * linv[r]);
    }
  }
}

extern "C" void kernel_launch(void* const* d_in, const int* in_sizes, int n_in,
                              void* d_out, int out_size, void* d_ws, size_t ws_size,
                              hipStream_t stream) {
  const float* x = (const float*)d_in[0];
  const int* pos = (const int*)d_in[1];
  const float* wdq = (const float*)d_in[2];
  const float* bdq = (const float*)d_in[3];
  const float* qnw = (const float*)d_in[4];
  const float* wuq = (const float*)d_in[5];
  const float* buq = (const float*)d_in[6];
  const float* wdkv = (const float*)d_in[7];
  const float* bdkv = (const float*)d_in[8];
  const float* kvnw = (const float*)d_in[9];
  const float* wukv = (const float*)d_in[10];
  const float* bukv = (const float*)d_in[11];
  const float* wo = (const float*)d_in[12];
  const float* bo = (const float*)d_in[13];
  float* out = (float*)d_out;

  char* ws = (char*)d_ws;
  size_t off = 0;
  auto alloc = [&](size_t bytes) {
    char* p = ws + off;
    off += (bytes + 255) & ~(size_t)255;
    return p;
  };
  // vT (16.78MB) aliases xbf_spacer+t0+qout_spacer (22MB): all dead/unused before
  // k_gemm_qkv runs. xbf is NO LONGER WRITTEN (r13: gemm-A reads x fp32 directly) and
  // qout is no longer written (stageb fused) -- both KEPT as spacers so the alias hole
  // stays >= vT size (removing either would shift wKVT into vT's range).
  u16* xbf = (u16*)alloc((size_t)R_TOK * 1024 * 2);    // UNUSED spacer (alias hole)
  float* t0 = (float*)alloc((size_t)R_TOK * 320 * 4);  // dead after stagea
  u16* qout = (u16*)alloc((size_t)R_TOK * 1024 * 2);   // UNUSED spacer (alias hole)
  u16* vT = (u16*)d_ws;                                // alias of the three above
  u16* waT = (u16*)alloc((size_t)384 * 1024 * 2);      // padded 320->384 rows
  float* biasA = (float*)alloc(320 * 4);
  u16* wQT = (u16*)alloc((size_t)1024 * 128 * 2);
  u16* wKVT = (u16*)alloc((size_t)2560 * 128 * 2);
  u16* wOT = (u16*)alloc((size_t)1024 * 2048 * 2);
  u16* cq = (u16*)alloc((size_t)R_TOK * 128 * 2);
  u16* ckv = (u16*)alloc((size_t)R_TOK * 128 * 2);
  u16* krope = (u16*)alloc((size_t)R_TOK * 64 * 2);
  u16* qst = (u16*)alloc((size_t)R_TOK * 1024 * 2);
  u16* kvb = (u16*)alloc((size_t)R_TOK * 2560 * 2);
  u16* attnb = (u16*)alloc((size_t)R_TOK * 2048 * 2);
  float* qtab = (float*)alloc((size_t)R_TOK * 16 * 2 * 4);  // q-rope cos/sin table, 512KB
  (void)ws_size; (void)n_in; (void)in_sizes; (void)out_size; (void)qout; (void)xbf;

  // prep part 1: waT transpose + biasA only (x->bf16 pass eliminated)
  k_prep1<<<321, 256, 0, stream>>>(wdq, wdkv, waT, bdq, bdkv, biasA);
  // gemm-A (96 blocks, A = x fp32 reg-staged) + later-stage weight transposes
  // (2496 blocks) in one launch: transposes fill the 160 CUs gemm-A leaves idle
  k_gemma_wt<<<2592, 256, 0, stream>>>(x, waT, biasA, t0,
                                       wuq, wQT, wukv, wKVT, wo, wOT);
  k_stagea<<<R_TOK, 128, 0, stream>>>(t0, qnw, kvnw, pos, cq, ckv, krope, qtab);
  // fused q + kv up-projections (independent): 256 q-blocks + 640 kv-blocks, one launch
  k_gemm_qkv<<<896, 256, 0, stream>>>(cq, wQT, buq, qtab, qst, ckv, wKVT, bukv, kvb, vT);
  // attention: 256 blocks (1/CU, 96KB LDS, 8 waves = 2/SIMD), 512 threads (r3-exact)
  k_attn<<<dim3(16, 16), 512, 0, stream>>>(qst, kvb, krope, vT, attnb);
  // output projection -> fp32 out
  k_gemm_bt<0><<<dim3(8, 32), 256, 0, stream>>>(attnb, wOT, bo, out, R_TOK, 1024, 2048);
}

// Round 14
// 248.739 us; speedup vs baseline: 1.0773x; 1.0773x over previous
//
#include <hip/hip_runtime.h>
#include <hip/hip_bf16.h>
#include <stdint.h>

typedef unsigned short u16;
typedef short short8 __attribute__((ext_vector_type(8)));
typedef float floatx4 __attribute__((ext_vector_type(4)));

#define S_LEN 2048
#define NB 2
#define NH 8
#define R_TOK (NB * S_LEN)  // 4096

#define L2_THETA 13.287712379549449f
// attention scale folded into Q, log2 domain: (1/sqrt(128)) * log2(e)
#define QSCALE (0.08838834764831845f * 1.4426950408889634f)

__device__ inline u16 f2bf(float f) {
  union { float f; uint32_t u; } x; x.f = f;
  uint32_t r = (x.u + 0x7fffu + ((x.u >> 16) & 1u)) >> 16;
  return (u16)r;
}
__device__ inline float bf2f(u16 h) {
  union { uint32_t u; float f; } x; x.u = ((uint32_t)h) << 16;
  return x.f;
}
__device__ inline floatx4 mfma16(short8 a, short8 b, floatx4 c) {
  return __builtin_amdgcn_mfma_f32_16x16x32_bf16(a, b, c, 0, 0, 0);
}
__device__ inline uint32_t pkbf(float a, float b) {
  union { __hip_bfloat162 h; uint32_t u; } c;
  c.h = __float22bfloat162_rn(make_float2(a, b));
  return c.u;
}
__device__ __forceinline__ void cp16(const void* g, const void* l) {
  __builtin_amdgcn_global_load_lds(
      (const __attribute__((address_space(1))) uint32_t*)(uintptr_t)g,
      (__attribute__((address_space(3))) uint32_t*)(uintptr_t)l, 16, 0, 0);
}

// ---------------- prep part 1 (r12-exact): x->bf16, waT transpose, biasA ----------------
// r13's fp32-direct gemm-A regressed +17us (tripled fp32 panel traffic + f2bf/ds_write
// inside the MFMA loop on the 96 critical-path blocks). The serial conversion pass is
// cheaper: full-chip BW, dead-simple. Reverted.
__global__ __launch_bounds__(256) void k_prep1(
    const float* __restrict__ x, u16* __restrict__ xbf,
    const float* __restrict__ wdq, const float* __restrict__ wdkv, u16* __restrict__ waT,
    const float* __restrict__ bdq, const float* __restrict__ bdkv,
    float* __restrict__ biasA) {
  __shared__ u16 tile[32][33];
  const int s = blockIdx.x, tid = threadIdx.x;
  const int tx = tid & 31, ty = tid >> 5;
  if (s < 4096) {
    int i = s * 256 + tid;
    float4 v = ((const float4*)x)[i];
    ushort4 o;
    o.x = f2bf(v.x); o.y = f2bf(v.y); o.z = f2bf(v.z); o.w = f2bf(v.w);
    ((ushort4*)xbf)[i] = o;
  } else if (s < 4416) {  // waT: logical [1024][320] -> [320][1024]
    int t = s - 4096, bx = t % 10, by = t / 10;
    int c0 = bx * 32, r0 = by * 32;
#pragma unroll
    for (int i = 0; i < 4; ++i) {
      int r = r0 + ty + i * 8, c = c0 + tx;
      float v = (c < 128) ? wdq[(size_t)r * 128 + c] : wdkv[(size_t)r * 192 + (c - 128)];
      tile[ty + i * 8][tx] = f2bf(v);
    }
    __syncthreads();
#pragma unroll
    for (int i = 0; i < 4; ++i)
      waT[(size_t)(c0 + ty + i * 8) * 1024 + r0 + tx] = tile[tx][ty + i * 8];
  } else {
    if (tid < 320) biasA[tid] = (tid < 128) ? bdq[tid] : bdkv[tid - 128];
  }
}

// ------- gemm-A + weight-transpose uber-kernel (r12-exact) -------
// blockIdx < 96: gemm path (xbf @ waT -> t0 fp32; M=4096 N=320 K=1024, 3n x 32m,
// k_gemm_bt-exact). Else: 32x32 weight transposes (wQT 128, wKVT 320, wOT 2048 blocks),
// independent of gemm inputs; fills the 160 CUs gemm-A leaves idle.
__global__ __launch_bounds__(256) void k_gemma_wt(
    const u16* __restrict__ A, const u16* __restrict__ BT,
    const float* __restrict__ bias, float* __restrict__ Cout,
    const float* __restrict__ wuq, u16* __restrict__ wQT,
    const float* __restrict__ wukv, u16* __restrict__ wKVT,
    const float* __restrict__ wo, u16* __restrict__ wOT) {
  const int tid = threadIdx.x;
  if (blockIdx.x >= 96) {  // ---- transpose path (block-uniform) ----
    __shared__ u16 tile[32][33];
    int t = blockIdx.x - 96;
    const float* in; u16* out; int R, C, bx, by;
    if (t < 128) { in = wuq; out = wQT; R = 128; C = 1024; bx = t & 31; by = t >> 5; }
    else if (t < 448) { int u = t - 128; in = wukv; out = wKVT; R = 128; C = 2560; bx = u % 80; by = u / 80; }
    else { int u = t - 448; in = wo; out = wOT; R = 2048; C = 1024; bx = u & 31; by = u >> 5; }
    const int tx = tid & 31, ty = tid >> 5;
    int c0 = bx * 32, r0 = by * 32;
#pragma unroll
    for (int i = 0; i < 4; ++i)
      tile[ty + i * 8][tx] = f2bf(in[(size_t)(r0 + ty + i * 8) * C + c0 + tx]);
    __syncthreads();
#pragma unroll
    for (int i = 0; i < 4; ++i)
      out[(size_t)(c0 + ty + i * 8) * R + r0 + tx] = tile[tx][ty + i * 8];
    return;
  }
  // ---- gemm path: M=4096, N=320, K=1024, fp32 out ----
  const int N = 320, K = 1024;
  __shared__ __align__(16) u16 Alds[2][128 * 32];
  __shared__ __align__(16) u16 Blds[2][128 * 32];
  const int wave = tid >> 6, lane = tid & 63;
  const int lane15 = lane & 15, quad = lane >> 4;
  const int n0 = (blockIdx.x % 3) * 128, m0 = (blockIdx.x / 3) * 128;
  const int mw = (wave & 1) * 64, nw = (wave >> 1) * 64;

  floatx4 acc[4][4];
#pragma unroll
  for (int a = 0; a < 4; ++a)
#pragma unroll
    for (int b = 0; b < 4; ++b) acc[a][b] = (floatx4){0.f, 0.f, 0.f, 0.f};

  const int srow = wave * 32 + (lane >> 2);
  const int scol = (lane & 3) * 8;
  auto stage = [&](int k0, int buf) {
    const u16* ga = A + (size_t)(m0 + srow) * K + k0 + scol;
    cp16(ga, Alds[buf] + srow * 32 + scol);
    cp16(ga + (size_t)16 * K, Alds[buf] + (srow + 16) * 32 + scol);
    const u16* gb = BT + (size_t)(n0 + srow) * K + k0 + scol;
    cp16(gb, Blds[buf] + srow * 32 + scol);
    cp16(gb + (size_t)16 * K, Blds[buf] + (srow + 16) * 32 + scol);
  };

  stage(0, 0);
  int cur = 0;
  for (int k0 = 0; k0 < K; k0 += 32) {
    __syncthreads();
    if (k0 + 32 < K) stage(k0 + 32, cur ^ 1);
    short8 af[4], bf[4];
#pragma unroll
    for (int im = 0; im < 4; ++im)
      af[im] = *(const short8*)&Alds[cur][(mw + im * 16 + lane15) * 32 + quad * 8];
#pragma unroll
    for (int in = 0; in < 4; ++in)
      bf[in] = *(const short8*)&Blds[cur][(nw + in * 16 + lane15) * 32 + quad * 8];
#pragma unroll
    for (int im = 0; im < 4; ++im)
#pragma unroll
      for (int in = 0; in < 4; ++in) acc[im][in] = mfma16(af[im], bf[in], acc[im][in]);
    cur ^= 1;
  }

#pragma unroll
  for (int im = 0; im < 4; ++im)
#pragma unroll
    for (int in = 0; in < 4; ++in)
#pragma unroll
      for (int r = 0; r < 4; ++r) {
        int row = m0 + mw + im * 16 + quad * 4 + r;
        int col = n0 + nw + in * 16 + lane15;
        if (col < N) Cout[(size_t)row * N + col] = acc[im][in][r] + bias[col];
      }
}

// ---------------- 128x128-tile GEMM, B transposed [N][K], double-buffered async ----------
template <int OUT_BF>
__global__ __launch_bounds__(256) void k_gemm_bt(const u16* __restrict__ A,
                                                 const u16* __restrict__ BT,
                                                 const float* __restrict__ bias,
                                                 void* __restrict__ Cout,
                                                 int M, int N, int K) {
  __shared__ __align__(16) u16 Alds[2][128 * 32];
  __shared__ __align__(16) u16 Blds[2][128 * 32];
  const int tid = threadIdx.x;
  const int wave = tid >> 6, lane = tid & 63;
  const int lane15 = lane & 15, quad = lane >> 4;
  const int m0 = blockIdx.y * 128, n0 = blockIdx.x * 128;
  const int mw = (wave & 1) * 64, nw = (wave >> 1) * 64;

  floatx4 acc[4][4];
#pragma unroll
  for (int a = 0; a < 4; ++a)
#pragma unroll
    for (int b = 0; b < 4; ++b) acc[a][b] = (floatx4){0.f, 0.f, 0.f, 0.f};

  const int srow = wave * 32 + (lane >> 2);
  const int scol = (lane & 3) * 8;

  auto stage = [&](int k0, int buf) {
    const u16* ga = A + (size_t)(m0 + srow) * K + k0 + scol;
    cp16(ga, Alds[buf] + srow * 32 + scol);
    cp16(ga + (size_t)16 * K, Alds[buf] + (srow + 16) * 32 + scol);
    const u16* gb = BT + (size_t)(n0 + srow) * K + k0 + scol;
    cp16(gb, Blds[buf] + srow * 32 + scol);
    cp16(gb + (size_t)16 * K, Blds[buf] + (srow + 16) * 32 + scol);
  };

  stage(0, 0);
  int cur = 0;
  for (int k0 = 0; k0 < K; k0 += 32) {
    __syncthreads();
    if (k0 + 32 < K) stage(k0 + 32, cur ^ 1);
    short8 af[4], bf[4];
#pragma unroll
    for (int im = 0; im < 4; ++im)
      af[im] = *(const short8*)&Alds[cur][(mw + im * 16 + lane15) * 32 + quad * 8];
#pragma unroll
    for (int in = 0; in < 4; ++in)
      bf[in] = *(const short8*)&Blds[cur][(nw + in * 16 + lane15) * 32 + quad * 8];
#pragma unroll
    for (int im = 0; im < 4; ++im)
#pragma unroll
      for (int in = 0; in < 4; ++in) acc[im][in] = mfma16(af[im], bf[in], acc[im][in]);
    cur ^= 1;
  }

#pragma unroll
  for (int im = 0; im < 4; ++im)
#pragma unroll
    for (int in = 0; in < 4; ++in)
#pragma unroll
      for (int r = 0; r < 4; ++r) {
        int row = m0 + mw + im * 16 + quad * 4 + r;
        int col = n0 + nw + in * 16 + lane15;
        if (col < N) {
          float v = acc[im][in][r] + bias[col];
          if (OUT_BF)
            ((u16*)Cout)[(size_t)row * N + col] = f2bf(v);
          else
            ((float*)Cout)[(size_t)row * N + col] = v;
        }
      }
}

// ------- fused Q+KV GEMM uber-kernel (r10) -------
// q and kv up-projections are mutually independent. One 896-block launch removes a
// launch gap and lets kv blocks fill the q-tail. blockIdx.x < 256: q-path, m-fastest
// mapping (XCD spread for rope blocks); else kv-path, n-fastest. Internals r8-exact.
__global__ __launch_bounds__(256) void k_gemm_qkv(
    const u16* __restrict__ Aq, const u16* __restrict__ BTq,
    const float* __restrict__ biasq, const float* __restrict__ qtab,
    u16* __restrict__ qstates,
    const u16* __restrict__ Akv, const u16* __restrict__ BTkv,
    const float* __restrict__ biaskv, u16* __restrict__ kvb, u16* __restrict__ vT) {
  const int K = 128;
  __shared__ __align__(16) u16 Alds[2][128 * 32];
  __shared__ __align__(16) u16 Blds[2][128 * 32];
  __shared__ __align__(16) u16 eplds[64 * 136];  // kv V-epilogue staging, 17.4 KB
  const int tid = threadIdx.x;
  const int wave = tid >> 6, lane = tid & 63;
  const int lane15 = lane & 15, quad = lane >> 4;
  const bool isq = blockIdx.x < 256;
  int m0, n0;
  const u16 *A, *BT;
  if (isq) {  // q: grid (32 m) x (8 n), m fastest
    int qb = blockIdx.x;
    m0 = (qb & 31) * 128;
    n0 = (qb >> 5) * 128;
    A = Aq; BT = BTq;
  } else {    // kv: grid (20 n) x (32 m), n fastest
    int kb = blockIdx.x - 256;
    n0 = (kb % 20) * 128;
    m0 = (kb / 20) * 128;
    A = Akv; BT = BTkv;
  }
  const int mw = (wave & 1) * 64, nw = (wave >> 1) * 64;

  floatx4 acc[4][4];
#pragma unroll
  for (int a = 0; a < 4; ++a)
#pragma unroll
    for (int b = 0; b < 4; ++b) acc[a][b] = (floatx4){0.f, 0.f, 0.f, 0.f};

  const int srow = wave * 32 + (lane >> 2);
  const int scol = (lane & 3) * 8;
  auto stage = [&](int k0, int buf) {
    const u16* ga = A + (size_t)(m0 + srow) * K + k0 + scol;
    cp16(ga, Alds[buf] + srow * 32 + scol);
    cp16(ga + (size_t)16 * K, Alds[buf] + (srow + 16) * 32 + scol);
    const u16* gb = BT + (size_t)(n0 + srow) * K + k0 + scol;
    cp16(gb, Blds[buf] + srow * 32 + scol);
    cp16(gb + (size_t)16 * K, Blds[buf] + (srow + 16) * 32 + scol);
  };

  stage(0, 0);
  int cur = 0;
  for (int k0 = 0; k0 < K; k0 += 32) {
    __syncthreads();
    if (k0 + 32 < K) stage(k0 + 32, cur ^ 1);
    short8 af[4], bf[4];
#pragma unroll
    for (int im = 0; im < 4; ++im)
      af[im] = *(const short8*)&Alds[cur][(mw + im * 16 + lane15) * 32 + quad * 8];
#pragma unroll
    for (int in = 0; in < 4; ++in)
      bf[in] = *(const short8*)&Blds[cur][(nw + in * 16 + lane15) * 32 + quad * 8];
#pragma unroll
    for (int im = 0; im < 4; ++im)
#pragma unroll
      for (int in = 0; in < 4; ++in) acc[im][in] = mfma16(af[im], bf[in], acc[im][in]);
    cur ^= 1;
  }

  if (isq) {  // ---- q epilogue: rope(table) + scale + scatter (r8-exact) ----
    const bool ropeblk = (n0 >= 768);
#pragma unroll
    for (int in = 0; in < 4; ++in) {
      const int col = n0 + nw + in * 16 + lane15;
#pragma unroll
      for (int im = 0; im < 4; ++im) {
        if (!ropeblk) {
          const int h = col / 96, d = col - h * 96;
#pragma unroll
          for (int r = 0; r < 4; ++r) {
            int row = m0 + mw + im * 16 + quad * 4 + r;
            int b = row >> 11, s = row & (S_LEN - 1);
            float v = acc[im][in][r] + biasq[col];
            qstates[((size_t)(b * NH + h) * S_LEN + s) * 128 + d] = f2bf(v * QSCALE);
          }
        } else {
          const int j = (col - 768) & 31, h = (col - 768) >> 5, pr = j >> 1;
#pragma unroll
          for (int r = 0; r < 4; ++r) {
            int row = m0 + mw + im * 16 + quad * 4 + r;
            int b = row >> 11, s = row & (S_LEN - 1);
            float v = acc[im][in][r] + biasq[col];
            float vp = __shfl_xor(v, 1);  // partner col^1 = lane15^1, same row
            float xe = (lane & 1) ? vp : v;
            float xo = (lane & 1) ? v : vp;
            float2 cs = *(const float2*)&qtab[((size_t)row * 16 + pr) * 2];  // (cos, sin)
            float val = (j & 1) ? (xe * cs.y + xo * cs.x) : (xe * cs.x - xo * cs.y);
            qstates[((size_t)(b * NH + h) * S_LEN + s) * 128 + 96 + j] = f2bf(val * QSCALE);
          }
        }
      }
    }
  } else if (n0 < 512) {  // ---- kv k_nope epilogue (r8-exact) ----
#pragma unroll
    for (int im = 0; im < 4; ++im)
#pragma unroll
      for (int in = 0; in < 4; ++in)
#pragma unroll
        for (int r = 0; r < 4; ++r) {
          int row = m0 + mw + im * 16 + quad * 4 + r;
          int col = n0 + nw + in * 16 + lane15;
          kvb[(size_t)row * 2560 + col] = f2bf(acc[im][in][r] + biaskv[col]);
        }
  } else {  // ---- kv V epilogue: two-pass LDS-staged coalesced vT write (r8-exact) ----
    const int sbase = m0 & (S_LEN - 1), bq = m0 >> 11;
#pragma unroll
    for (int hh = 0; hh < 2; ++hh) {
#pragma unroll
      for (int im = 0; im < 4; ++im) {
        const int rrel = mw + im * 16 + quad * 4;  // block-relative s, 0..127
        const int bb = (rrel & 63) >> 2;
        const int a = (bb & 8) | (((bb >> 1) & 1) << 2) | ((bb & 1) << 1) | ((bb >> 2) & 1);
        const int prel = (rrel >> 6) * 64 + a * 4;
#pragma unroll
        for (int ii = 0; ii < 2; ++ii) {
          const int in = hh * 2 + ii;
          const int nl = nw + in * 16 + lane15;
          const int slot = (nl & 31) | ((nl & 64) >> 1);
          const float bv = biaskv[n0 + nl];
          ushort4 o;
          o.x = f2bf(acc[im][in][0] + bv);
          o.y = f2bf(acc[im][in][1] + bv);
          o.z = f2bf(acc[im][in][2] + bv);
          o.w = f2bf(acc[im][in][3] + bv);
          *(ushort4*)&eplds[slot * 136 + prel] = o;
        }
      }
      __syncthreads();
#pragma unroll
      for (int i = 0; i < 4; ++i) {
        int idx = i * 256 + tid;
        int slot = idx >> 4, c8 = (idx & 15) * 8;
        int nl = (slot & 31) + hh * 32 + ((slot & 32) << 1);
        int c2 = n0 + nl - 512;
        int hv = c2 >> 8, nn = c2 & 255;
        short8 v = *(const short8*)&eplds[slot * 136 + c8];
        *(short8*)&vT[((size_t)((bq * NH + hv) * 256 + nn)) * 2048 + sbase + c8] = v;
      }
      if (hh == 0) __syncthreads();
    }
  }
}

// ------- stage-A epilogue: rmsnorm(cq), rmsnorm(ckv), rope(k_rope), q-rope table -------
__global__ void k_stagea(const float* __restrict__ t0, const float* __restrict__ qnw,
                         const float* __restrict__ kvnw, const int* __restrict__ pos_ids,
                         u16* __restrict__ cq, u16* __restrict__ ckv,
                         u16* __restrict__ krope, float* __restrict__ qtab) {
  int r = blockIdx.x, tid = threadIdx.x;  // 128 threads
  const float* row = t0 + (size_t)r * 320;
  float a = row[tid];
  float b = row[128 + tid];
  float sa = a * a, sb = b * b;
#pragma unroll
  for (int d = 1; d < 64; d <<= 1) {
    sa += __shfl_xor(sa, d);
    sb += __shfl_xor(sb, d);
  }
  __shared__ float red[4];
  if ((tid & 63) == 0) { red[(tid >> 6) * 2] = sa; red[(tid >> 6) * 2 + 1] = sb; }
  __syncthreads();
  sa = red[0] + red[2];
  sb = red[1] + red[3];
  float ra = rsqrtf(sa * (1.0f / 128.0f) + 1e-8f);
  float rb = rsqrtf(sb * (1.0f / 128.0f) + 1e-8f);
  cq[(size_t)r * 128 + tid] = f2bf(qnw[tid] * a * ra);
  ckv[(size_t)r * 128 + tid] = f2bf(kvnw[tid] * b * rb);
  if (tid < 32) {
    float xe = row[256 + 2 * tid], xo = row[256 + 2 * tid + 1];
    float p = (float)pos_ids[r];
    float freq = exp2f(-(2.0f * tid / 64.0f) * L2_THETA);
    float ang = p * freq;
    float c = cosf(ang), s = sinf(ang);
    krope[(size_t)r * 64 + 2 * tid] = f2bf(xe * c - xo * s);
    krope[(size_t)r * 64 + 2 * tid + 1] = f2bf(xe * s + xo * c);
  } else if (tid < 48) {
    // q-rope table: bitwise-identical formula to the old k_stageb path
    int pr = tid - 32;
    float p = (float)pos_ids[r];
    float freq = exp2f(-(2.0f * pr / 32.0f) * L2_THETA);
    float ang = p * freq;
    qtab[((size_t)r * 16 + pr) * 2] = cosf(ang);
    qtab[((size_t)r * 16 + pr) * 2 + 1] = sinf(ang);
  }
}

// ---------------- flash attention: 2-phase double-buffered pipeline (r3-exact) ----------
// Best-known attn: 88.1-90us, reproduced 7x. All deviations regressed: r5 n-split (+26%),
// r9 q-split (+17%, 1 wave/SIMD), r11 V-frag hoist (+2.5us, VGPR 88->100 perturbed the
// compiler's schedule). This structure is the banked floor -- do not edit.
__global__ __launch_bounds__(512) void k_attn(const u16* __restrict__ qstates,
                                              const u16* __restrict__ kv,
                                              const u16* __restrict__ krope,
                                              const u16* __restrict__ vT,
                                              u16* __restrict__ attn_out) {
  const int pair = blockIdx.x;  // 0..15 (pair-major: XCD = pair%8)
  const int qblk = blockIdx.y;  // 0..15
  const int b = pair >> 3, h = pair & 7;
  const int tid = threadIdx.x;
  const int wave = tid >> 6, lane = tid & 63;
  const int lane15 = lane & 15, quad = lane >> 4;
  const int w4 = wave & 3, half = wave >> 2;

  __shared__ __align__(16) u16 Klds[2][64 * 128];   // 2 x 16 KB
  __shared__ __align__(16) u16 Vlds[2][256 * 64];   // 2 x 32 KB

  const int qrow0 = qblk * 128 + wave * 16;
  short8 qfrag[4];
  {
    const u16* qb = qstates + ((size_t)(b * NH + h) * S_LEN + qrow0 + lane15) * 128 + quad * 8;
#pragma unroll
    for (int c = 0; c < 4; ++c) qfrag[c] = *(const short8*)(qb + c * 32);
  }

  floatx4 o_acc[16];
#pragma unroll
  for (int g = 0; g < 16; ++g) o_acc[g] = (floatx4){0.f, 0.f, 0.f, 0.f};
  float m_i = -1e30f;
  float l_i = 0.f;  // per-lane PARTIAL row-sum; reduced at epilogue

  // ---- hoisted, ch-invariant LDS read offsets (u16 units) ----
  const int kbase = (quad * 16 + lane15) * 8;  // + (t*16+c*4)*128 (imm)
  int vo0[4], vo1[4];
#pragma unroll
  for (int ph = 0; ph < 4; ++ph) {
    int n = ph * 16 + lane15;
    int sw = (n ^ (n >> 3)) & 7;
    vo0[ph] = n * 64 + ((quad ^ sw) & 7) * 8;
    vo1[ph] = n * 64 + (((quad | 4) ^ sw) & 7) * 8;
  }

  // K staging (512 thr, 2 cp16/thread): row = w4*16+lane15, unit u = half*8 + 4j + quad.
  const u16* kp[2];
  int kstr[2];
  int kdst[2];
#pragma unroll
  for (int j = 0; j < 2; ++j) {
    int u = half * 8 + j * 4 + quad;
    const u16* base;
    int str;
    if (u < 8) { base = kv + h * 64 + u * 8; str = 2560; }
    else { base = krope + (u - 8) * 8; str = 64; }
    kp[j] = base + (size_t)(b * S_LEN + w4 * 16 + lane15) * str;
    kstr[j] = str;
    kdst[j] = (w4 * 256 + (half * 2 + j) * 64 + lane) * 8;
  }
  // V staging (512 thr, 4 cp16/thread): n = oi*64 + (tid>>3), slot = tid&7
  const int vn6 = tid >> 3, vsl = tid & 7;
  const u16* vp[4];
#pragma unroll
  for (int oi = 0; oi < 4; ++oi) {
    int n = oi * 64 + vn6;
    int u = vsl ^ ((n ^ (n >> 3)) & 7);
    vp[oi] = vT + ((size_t)pair * 256 + n) * 2048 + u * 8;
  }

  auto issueK = [&](int buf) {
#pragma unroll
    for (int j = 0; j < 2; ++j) {
      cp16(kp[j], &Klds[buf][kdst[j]]);
      kp[j] += (size_t)64 * kstr[j];
    }
  };
  auto issueV = [&](int buf) {
#pragma unroll
    for (int oi = 0; oi < 4; ++oi) {
      cp16(vp[oi], &Vlds[buf][(oi * 512 + tid) * 8]);
      vp[oi] += 64;
    }
  };

  // prologue: fill buf0, drain, converge
  issueK(0);
  issueV(0);
  asm volatile("s_waitcnt vmcnt(0)" ::: "memory");
  __builtin_amdgcn_sched_barrier(0);
  __builtin_amdgcn_s_barrier();

  int cur = 0;
  for (int ch = 0; ch < S_LEN / 64; ++ch) {
    if (ch + 1 < S_LEN / 64) {
      issueK(cur ^ 1);
      issueV(cur ^ 1);
    }

    // S^T = K * Q^T : st[t][r] = S[q=lane15][k = t*16 + quad*4 + r] (log2 domain)
    floatx4 st[4];
#pragma unroll
    for (int t = 0; t < 4; ++t) st[t] = (floatx4){0.f, 0.f, 0.f, 0.f};
    __builtin_amdgcn_s_setprio(1);
#pragma unroll
    for (int c = 0; c < 4; ++c) {
      short8 qf = qfrag[c];
#pragma unroll
      for (int t = 0; t < 4; ++t) {
        short8 kf = *(const short8*)&Klds[cur][kbase + (t * 16 + c * 4) * 128];
        st[t] = mfma16(kf, qf, st[t]);
      }
    }
    __builtin_amdgcn_s_setprio(0);

    // row max: fmax tree + 2-shfl butterfly (l-sum reduce deferred to epilogue)
    float mloc = st[0][0];
#pragma unroll
    for (int t = 0; t < 4; ++t)
#pragma unroll
      for (int r = 0; r < 4; ++r) mloc = fmaxf(mloc, st[t][r]);
    mloc = fmaxf(mloc, __shfl_xor(mloc, 16));
    mloc = fmaxf(mloc, __shfl_xor(mloc, 32));

    // defer-max: only rescale when max grew by >8 (log2 domain); P bounded by 2^8
    const bool resc = __any(mloc > m_i + 8.0f);
    const float mref = resc ? fmaxf(m_i, mloc) : m_i;

    float rs = 0.f;
    union { short8 s; uint4 u; } a01, a23;
    {
      float p0, p1, p2, p3;
      p0 = exp2f(st[0][0] - mref); p1 = exp2f(st[0][1] - mref);
      p2 = exp2f(st[0][2] - mref); p3 = exp2f(st[0][3] - mref);
      rs += (p0 + p1) + (p2 + p3);
      a01.u.x = pkbf(p0, p1); a01.u.y = pkbf(p2, p3);
      p0 = exp2f(st[1][0] - mref); p1 = exp2f(st[1][1] - mref);
      p2 = exp2f(st[1][2] - mref); p3 = exp2f(st[1][3] - mref);
      rs += (p0 + p1) + (p2 + p3);
      a01.u.z = pkbf(p0, p1); a01.u.w = pkbf(p2, p3);
      p0 = exp2f(st[2][0] - mref); p1 = exp2f(st[2][1] - mref);
      p2 = exp2f(st[2][2] - mref); p3 = exp2f(st[2][3] - mref);
      rs += (p0 + p1) + (p2 + p3);
      a23.u.x = pkbf(p0, p1); a23.u.y = pkbf(p2, p3);
      p0 = exp2f(st[3][0] - mref); p1 = exp2f(st[3][1] - mref);
      p2 = exp2f(st[3][2] - mref); p3 = exp2f(st[3][3] - mref);
      rs += (p0 + p1) + (p2 + p3);
      a23.u.z = pkbf(p0, p1); a23.u.w = pkbf(p2, p3);
    }

    if (resc) {  // rare after chunk 0 (THR=8): alpha rescale of o_acc + l_i
      float alpha = exp2f(m_i - mref);
      m_i = mref;
      l_i = l_i * alpha + rs;
      float al[4];
#pragma unroll
      for (int r = 0; r < 4; ++r) al[r] = __shfl(alpha, quad * 4 + r, 16);
#pragma unroll
      for (int g = 0; g < 16; ++g) {
        o_acc[g][0] *= al[0]; o_acc[g][1] *= al[1];
        o_acc[g][2] *= al[2]; o_acc[g][3] *= al[3];
      }
    } else {
      l_i += rs;
    }

    // PV: b-frags are single b128 reads (permuted-k vT layout, hoisted bases)
    __builtin_amdgcn_s_setprio(1);
#pragma unroll
    for (int g = 0; g < 16; ++g) {
      short8 b01 = *(const short8*)&Vlds[cur][vo0[g & 3] + (g >> 2) * 4096];
      short8 b23 = *(const short8*)&Vlds[cur][vo1[g & 3] + (g >> 2) * 4096];
      floatx4 o = o_acc[g];
      o = mfma16(a01.s, b01, o);
      o = mfma16(a23.s, b23, o);
      o_acc[g] = o;
    }
    __builtin_amdgcn_s_setprio(0);

    // single per-chunk sync: next-chunk loads had all of compute to land;
    // barrier seals this chunk's LDS reads before buf[cur] is overwritten.
    asm volatile("s_waitcnt vmcnt(0)" ::: "memory");
    __builtin_amdgcn_sched_barrier(0);
    __builtin_amdgcn_s_barrier();
    cur ^= 1;
  }

  // epilogue: reduce the per-quad partial row-sums once, then normalize
  float lsum = l_i;
  lsum += __shfl_xor(lsum, 16);
  lsum += __shfl_xor(lsum, 32);
  float rl = 1.0f / lsum;
  float linv[4];
#pragma unroll
  for (int r = 0; r < 4; ++r) linv[r] = __shfl(rl, quad * 4 + r, 16);
#pragma unroll
  for (int g = 0; g < 16; ++g) {
#pragma unroll
    for (int r = 0; r < 4; ++r) {
      int row = qrow0 + quad * 4 + r;
      int col = h * 256 + g * 16 + lane15;
      attn_out[((size_t)b * S_LEN + row) * 2048 + col] = f2bf(o_acc[g][r] * linv[r]);
    }
  }
}

extern "C" void kernel_launch(void* const* d_in, const int* in_sizes, int n_in,
                              void* d_out, int out_size, void* d_ws, size_t ws_size,
                              hipStream_t stream) {
  const float* x = (const float*)d_in[0];
  const int* pos = (const int*)d_in[1];
  const float* wdq = (const float*)d_in[2];
  const float* bdq = (const float*)d_in[3];
  const float* qnw = (const float*)d_in[4];
  const float* wuq = (const float*)d_in[5];
  const float* buq = (const float*)d_in[6];
  const float* wdkv = (const float*)d_in[7];
  const float* bdkv = (const float*)d_in[8];
  const float* kvnw = (const float*)d_in[9];
  const float* wukv = (const float*)d_in[10];
  const float* bukv = (const float*)d_in[11];
  const float* wo = (const float*)d_in[12];
  const float* bo = (const float*)d_in[13];
  float* out = (float*)d_out;

  char* ws = (char*)d_ws;
  size_t off = 0;
  auto alloc = [&](size_t bytes) {
    char* p = ws + off;
    off += (bytes + 255) & ~(size_t)255;
    return p;
  };
  // vT (16.78MB) aliases xbf+t0+qout_spacer (22MB): all dead before k_gemm_qkv runs.
  // qout is no longer written (stageb fused) but KEPT as a spacer so the alias hole
  // stays >= vT size (removing it would shift wKVT into vT's range).
  u16* xbf = (u16*)alloc((size_t)R_TOK * 1024 * 2);    // dead after gemm A
  float* t0 = (float*)alloc((size_t)R_TOK * 320 * 4);  // dead after stagea
  u16* qout = (u16*)alloc((size_t)R_TOK * 1024 * 2);   // UNUSED spacer (alias hole)
  u16* vT = (u16*)d_ws;                                // alias of the three above
  u16* waT = (u16*)alloc((size_t)384 * 1024 * 2);      // padded 320->384 rows
  float* biasA = (float*)alloc(320 * 4);
  u16* wQT = (u16*)alloc((size_t)1024 * 128 * 2);
  u16* wKVT = (u16*)alloc((size_t)2560 * 128 * 2);
  u16* wOT = (u16*)alloc((size_t)1024 * 2048 * 2);
  u16* cq = (u16*)alloc((size_t)R_TOK * 128 * 2);
  u16* ckv = (u16*)alloc((size_t)R_TOK * 128 * 2);
  u16* krope = (u16*)alloc((size_t)R_TOK * 64 * 2);
  u16* qst = (u16*)alloc((size_t)R_TOK * 1024 * 2);
  u16* kvb = (u16*)alloc((size_t)R_TOK * 2560 * 2);
  u16* attnb = (u16*)alloc((size_t)R_TOK * 2048 * 2);
  float* qtab = (float*)alloc((size_t)R_TOK * 16 * 2 * 4);  // q-rope cos/sin table, 512KB
  (void)ws_size; (void)n_in; (void)in_sizes; (void)out_size; (void)qout;

  // prep part 1: x->bf16, waT, biasA (r12-exact)
  k_prep1<<<4417, 256, 0, stream>>>(x, xbf, wdq, wdkv, waT, bdq, bdkv, biasA);
  // gemm-A (96 blocks) + later-stage weight transposes (2496 blocks) in one launch
  k_gemma_wt<<<2592, 256, 0, stream>>>(xbf, waT, biasA, t0,
                                       wuq, wQT, wukv, wKVT, wo, wOT);
  k_stagea<<<R_TOK, 128, 0, stream>>>(t0, qnw, kvnw, pos, cq, ckv, krope, qtab);
  // fused q + kv up-projections (independent): 256 q-blocks + 640 kv-blocks, one launch
  k_gemm_qkv<<<896, 256, 0, stream>>>(cq, wQT, buq, qtab, qst, ckv, wKVT, bukv, kvb, vT);
  // attention: 256 blocks (1/CU, 96KB LDS, 8 waves = 2/SIMD), 512 threads (r3-exact)
  k_attn<<<dim3(16, 16), 512, 0, stream>>>(qst, kvb, krope, vT, attnb);
  // output projection -> fp32 out
  k_gemm_bt<0><<<dim3(8, 32), 256, 0, stream>>>(attnb, wOT, bo, out, R_TOK, 1024, 2048);
}

// Round 15
// 243.735 us; speedup vs baseline: 1.0994x; 1.0205x over previous
//
#include <hip/hip_runtime.h>
#include <hip/hip_bf16.h>
#include <stdint.h>

typedef unsigned short u16;
typedef short short8 __attribute__((ext_vector_type(8)));
typedef float floatx4 __attribute__((ext_vector_type(4)));

#define S_LEN 2048
#define NB 2
#define NH 8
#define R_TOK (NB * S_LEN)  // 4096

#define L2_THETA 13.287712379549449f
// attention scale folded into Q, log2 domain: (1/sqrt(128)) * log2(e)
#define QSCALE (0.08838834764831845f * 1.4426950408889634f)

__device__ inline u16 f2bf(float f) {
  union { float f; uint32_t u; } x; x.f = f;
  uint32_t r = (x.u + 0x7fffu + ((x.u >> 16) & 1u)) >> 16;
  return (u16)r;
}
__device__ inline float bf2f(u16 h) {
  union { uint32_t u; float f; } x; x.u = ((uint32_t)h) << 16;
  return x.f;
}
__device__ inline floatx4 mfma16(short8 a, short8 b, floatx4 c) {
  return __builtin_amdgcn_mfma_f32_16x16x32_bf16(a, b, c, 0, 0, 0);
}
__device__ inline uint32_t pkbf(float a, float b) {
  union { __hip_bfloat162 h; uint32_t u; } c;
  c.h = __float22bfloat162_rn(make_float2(a, b));
  return c.u;
}
__device__ __forceinline__ void cp16(const void* g, const void* l) {
  __builtin_amdgcn_global_load_lds(
      (const __attribute__((address_space(1))) uint32_t*)(uintptr_t)g,
      (__attribute__((address_space(3))) uint32_t*)(uintptr_t)l, 16, 0, 0);
}

// ---------------- prep part 1 (r12-exact): x->bf16, waT transpose, biasA ----------------
__global__ __launch_bounds__(256) void k_prep1(
    const float* __restrict__ x, u16* __restrict__ xbf,
    const float* __restrict__ wdq, const float* __restrict__ wdkv, u16* __restrict__ waT,
    const float* __restrict__ bdq, const float* __restrict__ bdkv,
    float* __restrict__ biasA) {
  __shared__ u16 tile[32][33];
  const int s = blockIdx.x, tid = threadIdx.x;
  const int tx = tid & 31, ty = tid >> 5;
  if (s < 4096) {
    int i = s * 256 + tid;
    float4 v = ((const float4*)x)[i];
    ushort4 o;
    o.x = f2bf(v.x); o.y = f2bf(v.y); o.z = f2bf(v.z); o.w = f2bf(v.w);
    ((ushort4*)xbf)[i] = o;
  } else if (s < 4416) {  // waT: logical [1024][320] -> [320][1024]
    int t = s - 4096, bx = t % 10, by = t / 10;
    int c0 = bx * 32, r0 = by * 32;
#pragma unroll
    for (int i = 0; i < 4; ++i) {
      int r = r0 + ty + i * 8, c = c0 + tx;
      float v = (c < 128) ? wdq[(size_t)r * 128 + c] : wdkv[(size_t)r * 192 + (c - 128)];
      tile[ty + i * 8][tx] = f2bf(v);
    }
    __syncthreads();
#pragma unroll
    for (int i = 0; i < 4; ++i)
      waT[(size_t)(c0 + ty + i * 8) * 1024 + r0 + tx] = tile[tx][ty + i * 8];
  } else {
    if (tid < 320) biasA[tid] = (tid < 128) ? bdq[tid] : bdkv[tid - 128];
  }
}

// ------- gemm-A + weight-transpose uber-kernel (r12-exact) -------
__global__ __launch_bounds__(256) void k_gemma_wt(
    const u16* __restrict__ A, const u16* __restrict__ BT,
    const float* __restrict__ bias, float* __restrict__ Cout,
    const float* __restrict__ wuq, u16* __restrict__ wQT,
    const float* __restrict__ wukv, u16* __restrict__ wKVT,
    const float* __restrict__ wo, u16* __restrict__ wOT) {
  const int tid = threadIdx.x;
  if (blockIdx.x >= 96) {  // ---- transpose path (block-uniform) ----
    __shared__ u16 tile[32][33];
    int t = blockIdx.x - 96;
    const float* in; u16* out; int R, C, bx, by;
    if (t < 128) { in = wuq; out = wQT; R = 128; C = 1024; bx = t & 31; by = t >> 5; }
    else if (t < 448) { int u = t - 128; in = wukv; out = wKVT; R = 128; C = 2560; bx = u % 80; by = u / 80; }
    else { int u = t - 448; in = wo; out = wOT; R = 2048; C = 1024; bx = u & 31; by = u >> 5; }
    const int tx = tid & 31, ty = tid >> 5;
    int c0 = bx * 32, r0 = by * 32;
#pragma unroll
    for (int i = 0; i < 4; ++i)
      tile[ty + i * 8][tx] = f2bf(in[(size_t)(r0 + ty + i * 8) * C + c0 + tx]);
    __syncthreads();
#pragma unroll
    for (int i = 0; i < 4; ++i)
      out[(size_t)(c0 + ty + i * 8) * R + r0 + tx] = tile[tx][ty + i * 8];
    return;
  }
  // ---- gemm path: M=4096, N=320, K=1024, fp32 out ----
  const int N = 320, K = 1024;
  __shared__ __align__(16) u16 Alds[2][128 * 32];
  __shared__ __align__(16) u16 Blds[2][128 * 32];
  const int wave = tid >> 6, lane = tid & 63;
  const int lane15 = lane & 15, quad = lane >> 4;
  const int n0 = (blockIdx.x % 3) * 128, m0 = (blockIdx.x / 3) * 128;
  const int mw = (wave & 1) * 64, nw = (wave >> 1) * 64;

  floatx4 acc[4][4];
#pragma unroll
  for (int a = 0; a < 4; ++a)
#pragma unroll
    for (int b = 0; b < 4; ++b) acc[a][b] = (floatx4){0.f, 0.f, 0.f, 0.f};

  const int srow = wave * 32 + (lane >> 2);
  const int scol = (lane & 3) * 8;
  auto stage = [&](int k0, int buf) {
    const u16* ga = A + (size_t)(m0 + srow) * K + k0 + scol;
    cp16(ga, Alds[buf] + srow * 32 + scol);
    cp16(ga + (size_t)16 * K, Alds[buf] + (srow + 16) * 32 + scol);
    const u16* gb = BT + (size_t)(n0 + srow) * K + k0 + scol;
    cp16(gb, Blds[buf] + srow * 32 + scol);
    cp16(gb + (size_t)16 * K, Blds[buf] + (srow + 16) * 32 + scol);
  };

  stage(0, 0);
  int cur = 0;
  for (int k0 = 0; k0 < K; k0 += 32) {
    __syncthreads();
    if (k0 + 32 < K) stage(k0 + 32, cur ^ 1);
    short8 af[4], bf[4];
#pragma unroll
    for (int im = 0; im < 4; ++im)
      af[im] = *(const short8*)&Alds[cur][(mw + im * 16 + lane15) * 32 + quad * 8];
#pragma unroll
    for (int in = 0; in < 4; ++in)
      bf[in] = *(const short8*)&Blds[cur][(nw + in * 16 + lane15) * 32 + quad * 8];
#pragma unroll
    for (int im = 0; im < 4; ++im)
#pragma unroll
      for (int in = 0; in < 4; ++in) acc[im][in] = mfma16(af[im], bf[in], acc[im][in]);
    cur ^= 1;
  }

#pragma unroll
  for (int im = 0; im < 4; ++im)
#pragma unroll
    for (int in = 0; in < 4; ++in)
#pragma unroll
      for (int r = 0; r < 4; ++r) {
        int row = m0 + mw + im * 16 + quad * 4 + r;
        int col = n0 + nw + in * 16 + lane15;
        if (col < N) Cout[(size_t)row * N + col] = acc[im][in][r] + bias[col];
      }
}

// ------- out-projection GEMM, 64x128 tile (r15) -------
// attnb @ wOT + bo -> out fp32. M=4096, N=1024, K=2048. The 128x128 tiling gave grid
// 256 = 1 block/CU = 1 wave/SIMD (grid-capped, not resource-capped) -- the exact
// latency-exposure pathology that cost r9's attn +17%. 64x128 tile -> grid (8,64) =
// 512 blocks = 2 blocks/CU = 2 waves/SIMD, the validated sweet spot. LDS 24KB.
// Output bitwise-identical (same MFMA shape, same K-chunk order per element).
__global__ __launch_bounds__(256) void k_gemm_o(const u16* __restrict__ A,
                                                const u16* __restrict__ BT,
                                                const float* __restrict__ bias,
                                                float* __restrict__ Cout) {
  const int N = 1024, K = 2048;
  __shared__ __align__(16) u16 Alds[2][64 * 32];    // 2 x 4 KB
  __shared__ __align__(16) u16 Blds[2][128 * 32];   // 2 x 8 KB
  const int tid = threadIdx.x;
  const int wave = tid >> 6, lane = tid & 63;
  const int lane15 = lane & 15, quad = lane >> 4;
  const int m0 = blockIdx.y * 64, n0 = blockIdx.x * 128;

  floatx4 acc[4][2];
#pragma unroll
  for (int a = 0; a < 4; ++a)
#pragma unroll
    for (int b = 0; b < 2; ++b) acc[a][b] = (floatx4){0.f, 0.f, 0.f, 0.f};

  // A staging: 1 cp16/thread -> 64 rows x 32 cols (row=tid>>2, colgroup=(tid&3)*8)
  const int arow = tid >> 2, acg = (tid & 3) * 8;
  // B staging: 2 cp16/thread (r14 map): rows wave*32+(lane>>2) and +16
  const int srow = wave * 32 + (lane >> 2);
  const int scol = (lane & 3) * 8;
  auto stage = [&](int k0, int buf) {
    cp16(A + (size_t)(m0 + arow) * K + k0 + acg, Alds[buf] + arow * 32 + acg);
    const u16* gb = BT + (size_t)(n0 + srow) * K + k0 + scol;
    cp16(gb, Blds[buf] + srow * 32 + scol);
    cp16(gb + (size_t)16 * K, Blds[buf] + (srow + 16) * 32 + scol);
  };

  stage(0, 0);
  int cur = 0;
  for (int k0 = 0; k0 < K; k0 += 32) {
    __syncthreads();
    if (k0 + 32 < K) stage(k0 + 32, cur ^ 1);
    short8 af[4], bf[2];
#pragma unroll
    for (int im = 0; im < 4; ++im)
      af[im] = *(const short8*)&Alds[cur][(im * 16 + lane15) * 32 + quad * 8];
#pragma unroll
    for (int in = 0; in < 2; ++in)
      bf[in] = *(const short8*)&Blds[cur][(wave * 32 + in * 16 + lane15) * 32 + quad * 8];
#pragma unroll
    for (int im = 0; im < 4; ++im)
#pragma unroll
      for (int in = 0; in < 2; ++in) acc[im][in] = mfma16(af[im], bf[in], acc[im][in]);
    cur ^= 1;
  }

#pragma unroll
  for (int im = 0; im < 4; ++im)
#pragma unroll
    for (int in = 0; in < 2; ++in)
#pragma unroll
      for (int r = 0; r < 4; ++r) {
        int row = m0 + im * 16 + quad * 4 + r;
        int col = n0 + wave * 32 + in * 16 + lane15;
        Cout[(size_t)row * N + col] = acc[im][in][r] + bias[col];
      }
}

// ------- fused Q+KV GEMM uber-kernel (r10-exact) -------
__global__ __launch_bounds__(256) void k_gemm_qkv(
    const u16* __restrict__ Aq, const u16* __restrict__ BTq,
    const float* __restrict__ biasq, const float* __restrict__ qtab,
    u16* __restrict__ qstates,
    const u16* __restrict__ Akv, const u16* __restrict__ BTkv,
    const float* __restrict__ biaskv, u16* __restrict__ kvb, u16* __restrict__ vT) {
  const int K = 128;
  __shared__ __align__(16) u16 Alds[2][128 * 32];
  __shared__ __align__(16) u16 Blds[2][128 * 32];
  __shared__ __align__(16) u16 eplds[64 * 136];  // kv V-epilogue staging, 17.4 KB
  const int tid = threadIdx.x;
  const int wave = tid >> 6, lane = tid & 63;
  const int lane15 = lane & 15, quad = lane >> 4;
  const bool isq = blockIdx.x < 256;
  int m0, n0;
  const u16 *A, *BT;
  if (isq) {  // q: grid (32 m) x (8 n), m fastest
    int qb = blockIdx.x;
    m0 = (qb & 31) * 128;
    n0 = (qb >> 5) * 128;
    A = Aq; BT = BTq;
  } else {    // kv: grid (20 n) x (32 m), n fastest
    int kb = blockIdx.x - 256;
    n0 = (kb % 20) * 128;
    m0 = (kb / 20) * 128;
    A = Akv; BT = BTkv;
  }
  const int mw = (wave & 1) * 64, nw = (wave >> 1) * 64;

  floatx4 acc[4][4];
#pragma unroll
  for (int a = 0; a < 4; ++a)
#pragma unroll
    for (int b = 0; b < 4; ++b) acc[a][b] = (floatx4){0.f, 0.f, 0.f, 0.f};

  const int srow = wave * 32 + (lane >> 2);
  const int scol = (lane & 3) * 8;
  auto stage = [&](int k0, int buf) {
    const u16* ga = A + (size_t)(m0 + srow) * K + k0 + scol;
    cp16(ga, Alds[buf] + srow * 32 + scol);
    cp16(ga + (size_t)16 * K, Alds[buf] + (srow + 16) * 32 + scol);
    const u16* gb = BT + (size_t)(n0 + srow) * K + k0 + scol;
    cp16(gb, Blds[buf] + srow * 32 + scol);
    cp16(gb + (size_t)16 * K, Blds[buf] + (srow + 16) * 32 + scol);
  };

  stage(0, 0);
  int cur = 0;
  for (int k0 = 0; k0 < K; k0 += 32) {
    __syncthreads();
    if (k0 + 32 < K) stage(k0 + 32, cur ^ 1);
    short8 af[4], bf[4];
#pragma unroll
    for (int im = 0; im < 4; ++im)
      af[im] = *(const short8*)&Alds[cur][(mw + im * 16 + lane15) * 32 + quad * 8];
#pragma unroll
    for (int in = 0; in < 4; ++in)
      bf[in] = *(const short8*)&Blds[cur][(nw + in * 16 + lane15) * 32 + quad * 8];
#pragma unroll
    for (int im = 0; im < 4; ++im)
#pragma unroll
      for (int in = 0; in < 4; ++in) acc[im][in] = mfma16(af[im], bf[in], acc[im][in]);
    cur ^= 1;
  }

  if (isq) {  // ---- q epilogue: rope(table) + scale + scatter (r8-exact) ----
    const bool ropeblk = (n0 >= 768);
#pragma unroll
    for (int in = 0; in < 4; ++in) {
      const int col = n0 + nw + in * 16 + lane15;
#pragma unroll
      for (int im = 0; im < 4; ++im) {
        if (!ropeblk) {
          const int h = col / 96, d = col - h * 96;
#pragma unroll
          for (int r = 0; r < 4; ++r) {
            int row = m0 + mw + im * 16 + quad * 4 + r;
            int b = row >> 11, s = row & (S_LEN - 1);
            float v = acc[im][in][r] + biasq[col];
            qstates[((size_t)(b * NH + h) * S_LEN + s) * 128 + d] = f2bf(v * QSCALE);
          }
        } else {
          const int j = (col - 768) & 31, h = (col - 768) >> 5, pr = j >> 1;
#pragma unroll
          for (int r = 0; r < 4; ++r) {
            int row = m0 + mw + im * 16 + quad * 4 + r;
            int b = row >> 11, s = row & (S_LEN - 1);
            float v = acc[im][in][r] + biasq[col];
            float vp = __shfl_xor(v, 1);  // partner col^1 = lane15^1, same row
            float xe = (lane & 1) ? vp : v;
            float xo = (lane & 1) ? v : vp;
            float2 cs = *(const float2*)&qtab[((size_t)row * 16 + pr) * 2];  // (cos, sin)
            float val = (j & 1) ? (xe * cs.y + xo * cs.x) : (xe * cs.x - xo * cs.y);
            qstates[((size_t)(b * NH + h) * S_LEN + s) * 128 + 96 + j] = f2bf(val * QSCALE);
          }
        }
      }
    }
  } else if (n0 < 512) {  // ---- kv k_nope epilogue (r8-exact) ----
#pragma unroll
    for (int im = 0; im < 4; ++im)
#pragma unroll
      for (int in = 0; in < 4; ++in)
#pragma unroll
        for (int r = 0; r < 4; ++r) {
          int row = m0 + mw + im * 16 + quad * 4 + r;
          int col = n0 + nw + in * 16 + lane15;
          kvb[(size_t)row * 2560 + col] = f2bf(acc[im][in][r] + biaskv[col]);
        }
  } else {  // ---- kv V epilogue: two-pass LDS-staged coalesced vT write (r8-exact) ----
    const int sbase = m0 & (S_LEN - 1), bq = m0 >> 11;
#pragma unroll
    for (int hh = 0; hh < 2; ++hh) {
#pragma unroll
      for (int im = 0; im < 4; ++im) {
        const int rrel = mw + im * 16 + quad * 4;  // block-relative s, 0..127
        const int bb = (rrel & 63) >> 2;
        const int a = (bb & 8) | (((bb >> 1) & 1) << 2) | ((bb & 1) << 1) | ((bb >> 2) & 1);
        const int prel = (rrel >> 6) * 64 + a * 4;
#pragma unroll
        for (int ii = 0; ii < 2; ++ii) {
          const int in = hh * 2 + ii;
          const int nl = nw + in * 16 + lane15;
          const int slot = (nl & 31) | ((nl & 64) >> 1);
          const float bv = biaskv[n0 + nl];
          ushort4 o;
          o.x = f2bf(acc[im][in][0] + bv);
          o.y = f2bf(acc[im][in][1] + bv);
          o.z = f2bf(acc[im][in][2] + bv);
          o.w = f2bf(acc[im][in][3] + bv);
          *(ushort4*)&eplds[slot * 136 + prel] = o;
        }
      }
      __syncthreads();
#pragma unroll
      for (int i = 0; i < 4; ++i) {
        int idx = i * 256 + tid;
        int slot = idx >> 4, c8 = (idx & 15) * 8;
        int nl = (slot & 31) + hh * 32 + ((slot & 32) << 1);
        int c2 = n0 + nl - 512;
        int hv = c2 >> 8, nn = c2 & 255;
        short8 v = *(const short8*)&eplds[slot * 136 + c8];
        *(short8*)&vT[((size_t)((bq * NH + hv) * 256 + nn)) * 2048 + sbase + c8] = v;
      }
      if (hh == 0) __syncthreads();
    }
  }
}

// ------- stage-A epilogue: rmsnorm(cq), rmsnorm(ckv), rope(k_rope), q-rope table -------
__global__ void k_stagea(const float* __restrict__ t0, const float* __restrict__ qnw,
                         const float* __restrict__ kvnw, const int* __restrict__ pos_ids,
                         u16* __restrict__ cq, u16* __restrict__ ckv,
                         u16* __restrict__ krope, float* __restrict__ qtab) {
  int r = blockIdx.x, tid = threadIdx.x;  // 128 threads
  const float* row = t0 + (size_t)r * 320;
  float a = row[tid];
  float b = row[128 + tid];
  float sa = a * a, sb = b * b;
#pragma unroll
  for (int d = 1; d < 64; d <<= 1) {
    sa += __shfl_xor(sa, d);
    sb += __shfl_xor(sb, d);
  }
  __shared__ float red[4];
  if ((tid & 63) == 0) { red[(tid >> 6) * 2] = sa; red[(tid >> 6) * 2 + 1] = sb; }
  __syncthreads();
  sa = red[0] + red[2];
  sb = red[1] + red[3];
  float ra = rsqrtf(sa * (1.0f / 128.0f) + 1e-8f);
  float rb = rsqrtf(sb * (1.0f / 128.0f) + 1e-8f);
  cq[(size_t)r * 128 + tid] = f2bf(qnw[tid] * a * ra);
  ckv[(size_t)r * 128 + tid] = f2bf(kvnw[tid] * b * rb);
  if (tid < 32) {
    float xe = row[256 + 2 * tid], xo = row[256 + 2 * tid + 1];
    float p = (float)pos_ids[r];
    float freq = exp2f(-(2.0f * tid / 64.0f) * L2_THETA);
    float ang = p * freq;
    float c = cosf(ang), s = sinf(ang);
    krope[(size_t)r * 64 + 2 * tid] = f2bf(xe * c - xo * s);
    krope[(size_t)r * 64 + 2 * tid + 1] = f2bf(xe * s + xo * c);
  } else if (tid < 48) {
    // q-rope table: bitwise-identical formula to the old k_stageb path
    int pr = tid - 32;
    float p = (float)pos_ids[r];
    float freq = exp2f(-(2.0f * pr / 32.0f) * L2_THETA);
    float ang = p * freq;
    qtab[((size_t)r * 16 + pr) * 2] = cosf(ang);
    qtab[((size_t)r * 16 + pr) * 2 + 1] = sinf(ang);
  }
}

// ---------------- flash attention: 2-phase double-buffered pipeline (r3-exact) ----------
// Best-known attn: 88.1-90us, reproduced 8x. All deviations regressed: r5 n-split (+26%),
// r9 q-split (+17%, 1 wave/SIMD), r11 V-frag hoist (+2.5us, schedule perturbation).
// This structure is the banked floor -- do not edit.
__global__ __launch_bounds__(512) void k_attn(const u16* __restrict__ qstates,
                                              const u16* __restrict__ kv,
                                              const u16* __restrict__ krope,
                                              const u16* __restrict__ vT,
                                              u16* __restrict__ attn_out) {
  const int pair = blockIdx.x;  // 0..15 (pair-major: XCD = pair%8)
  const int qblk = blockIdx.y;  // 0..15
  const int b = pair >> 3, h = pair & 7;
  const int tid = threadIdx.x;
  const int wave = tid >> 6, lane = tid & 63;
  const int lane15 = lane & 15, quad = lane >> 4;
  const int w4 = wave & 3, half = wave >> 2;

  __shared__ __align__(16) u16 Klds[2][64 * 128];   // 2 x 16 KB
  __shared__ __align__(16) u16 Vlds[2][256 * 64];   // 2 x 32 KB

  const int qrow0 = qblk * 128 + wave * 16;
  short8 qfrag[4];
  {
    const u16* qb = qstates + ((size_t)(b * NH + h) * S_LEN + qrow0 + lane15) * 128 + quad * 8;
#pragma unroll
    for (int c = 0; c < 4; ++c) qfrag[c] = *(const short8*)(qb + c * 32);
  }

  floatx4 o_acc[16];
#pragma unroll
  for (int g = 0; g < 16; ++g) o_acc[g] = (floatx4){0.f, 0.f, 0.f, 0.f};
  float m_i = -1e30f;
  float l_i = 0.f;  // per-lane PARTIAL row-sum; reduced at epilogue

  // ---- hoisted, ch-invariant LDS read offsets (u16 units) ----
  const int kbase = (quad * 16 + lane15) * 8;  // + (t*16+c*4)*128 (imm)
  int vo0[4], vo1[4];
#pragma unroll
  for (int ph = 0; ph < 4; ++ph) {
    int n = ph * 16 + lane15;
    int sw = (n ^ (n >> 3)) & 7;
    vo0[ph] = n * 64 + ((quad ^ sw) & 7) * 8;
    vo1[ph] = n * 64 + (((quad | 4) ^ sw) & 7) * 8;
  }

  // K staging (512 thr, 2 cp16/thread): row = w4*16+lane15, unit u = half*8 + 4j + quad.
  const u16* kp[2];
  int kstr[2];
  int kdst[2];
#pragma unroll
  for (int j = 0; j < 2; ++j) {
    int u = half * 8 + j * 4 + quad;
    const u16* base;
    int str;
    if (u < 8) { base = kv + h * 64 + u * 8; str = 2560; }
    else { base = krope + (u - 8) * 8; str = 64; }
    kp[j] = base + (size_t)(b * S_LEN + w4 * 16 + lane15) * str;
    kstr[j] = str;
    kdst[j] = (w4 * 256 + (half * 2 + j) * 64 + lane) * 8;
  }
  // V staging (512 thr, 4 cp16/thread): n = oi*64 + (tid>>3), slot = tid&7
  const int vn6 = tid >> 3, vsl = tid & 7;
  const u16* vp[4];
#pragma unroll
  for (int oi = 0; oi < 4; ++oi) {
    int n = oi * 64 + vn6;
    int u = vsl ^ ((n ^ (n >> 3)) & 7);
    vp[oi] = vT + ((size_t)pair * 256 + n) * 2048 + u * 8;
  }

  auto issueK = [&](int buf) {
#pragma unroll
    for (int j = 0; j < 2; ++j) {
      cp16(kp[j], &Klds[buf][kdst[j]]);
      kp[j] += (size_t)64 * kstr[j];
    }
  };
  auto issueV = [&](int buf) {
#pragma unroll
    for (int oi = 0; oi < 4; ++oi) {
      cp16(vp[oi], &Vlds[buf][(oi * 512 + tid) * 8]);
      vp[oi] += 64;
    }
  };

  // prologue: fill buf0, drain, converge
  issueK(0);
  issueV(0);
  asm volatile("s_waitcnt vmcnt(0)" ::: "memory");
  __builtin_amdgcn_sched_barrier(0);
  __builtin_amdgcn_s_barrier();

  int cur = 0;
  for (int ch = 0; ch < S_LEN / 64; ++ch) {
    if (ch + 1 < S_LEN / 64) {
      issueK(cur ^ 1);
      issueV(cur ^ 1);
    }

    // S^T = K * Q^T : st[t][r] = S[q=lane15][k = t*16 + quad*4 + r] (log2 domain)
    floatx4 st[4];
#pragma unroll
    for (int t = 0; t < 4; ++t) st[t] = (floatx4){0.f, 0.f, 0.f, 0.f};
    __builtin_amdgcn_s_setprio(1);
#pragma unroll
    for (int c = 0; c < 4; ++c) {
      short8 qf = qfrag[c];
#pragma unroll
      for (int t = 0; t < 4; ++t) {
        short8 kf = *(const short8*)&Klds[cur][kbase + (t * 16 + c * 4) * 128];
        st[t] = mfma16(kf, qf, st[t]);
      }
    }
    __builtin_amdgcn_s_setprio(0);

    // row max: fmax tree + 2-shfl butterfly (l-sum reduce deferred to epilogue)
    float mloc = st[0][0];
#pragma unroll
    for (int t = 0; t < 4; ++t)
#pragma unroll
      for (int r = 0; r < 4; ++r) mloc = fmaxf(mloc, st[t][r]);
    mloc = fmaxf(mloc, __shfl_xor(mloc, 16));
    mloc = fmaxf(mloc, __shfl_xor(mloc, 32));

    // defer-max: only rescale when max grew by >8 (log2 domain); P bounded by 2^8
    const bool resc = __any(mloc > m_i + 8.0f);
    const float mref = resc ? fmaxf(m_i, mloc) : m_i;

    float rs = 0.f;
    union { short8 s; uint4 u; } a01, a23;
    {
      float p0, p1, p2, p3;
      p0 = exp2f(st[0][0] - mref); p1 = exp2f(st[0][1] - mref);
      p2 = exp2f(st[0][2] - mref); p3 = exp2f(st[0][3] - mref);
      rs += (p0 + p1) + (p2 + p3);
      a01.u.x = pkbf(p0, p1); a01.u.y = pkbf(p2, p3);
      p0 = exp2f(st[1][0] - mref); p1 = exp2f(st[1][1] - mref);
      p2 = exp2f(st[1][2] - mref); p3 = exp2f(st[1][3] - mref);
      rs += (p0 + p1) + (p2 + p3);
      a01.u.z = pkbf(p0, p1); a01.u.w = pkbf(p2, p3);
      p0 = exp2f(st[2][0] - mref); p1 = exp2f(st[2][1] - mref);
      p2 = exp2f(st[2][2] - mref); p3 = exp2f(st[2][3] - mref);
      rs += (p0 + p1) + (p2 + p3);
      a23.u.x = pkbf(p0, p1); a23.u.y = pkbf(p2, p3);
      p0 = exp2f(st[3][0] - mref); p1 = exp2f(st[3][1] - mref);
      p2 = exp2f(st[3][2] - mref); p3 = exp2f(st[3][3] - mref);
      rs += (p0 + p1) + (p2 + p3);
      a23.u.z = pkbf(p0, p1); a23.u.w = pkbf(p2, p3);
    }

    if (resc) {  // rare after chunk 0 (THR=8): alpha rescale of o_acc + l_i
      float alpha = exp2f(m_i - mref);
      m_i = mref;
      l_i = l_i * alpha + rs;
      float al[4];
#pragma unroll
      for (int r = 0; r < 4; ++r) al[r] = __shfl(alpha, quad * 4 + r, 16);
#pragma unroll
      for (int g = 0; g < 16; ++g) {
        o_acc[g][0] *= al[0]; o_acc[g][1] *= al[1];
        o_acc[g][2] *= al[2]; o_acc[g][3] *= al[3];
      }
    } else {
      l_i += rs;
    }

    // PV: b-frags are single b128 reads (permuted-k vT layout, hoisted bases)
    __builtin_amdgcn_s_setprio(1);
#pragma unroll
    for (int g = 0; g < 16; ++g) {
      short8 b01 = *(const short8*)&Vlds[cur][vo0[g & 3] + (g >> 2) * 4096];
      short8 b23 = *(const short8*)&Vlds[cur][vo1[g & 3] + (g >> 2) * 4096];
      floatx4 o = o_acc[g];
      o = mfma16(a01.s, b01, o);
      o = mfma16(a23.s, b23, o);
      o_acc[g] = o;
    }
    __builtin_amdgcn_s_setprio(0);

    // single per-chunk sync: next-chunk loads had all of compute to land;
    // barrier seals this chunk's LDS reads before buf[cur] is overwritten.
    asm volatile("s_waitcnt vmcnt(0)" ::: "memory");
    __builtin_amdgcn_sched_barrier(0);
    __builtin_amdgcn_s_barrier();
    cur ^= 1;
  }

  // epilogue: reduce the per-quad partial row-sums once, then normalize
  float lsum = l_i;
  lsum += __shfl_xor(lsum, 16);
  lsum += __shfl_xor(lsum, 32);
  float rl = 1.0f / lsum;
  float linv[4];
#pragma unroll
  for (int r = 0; r < 4; ++r) linv[r] = __shfl(rl, quad * 4 + r, 16);
#pragma unroll
  for (int g = 0; g < 16; ++g) {
#pragma unroll
    for (int r = 0; r < 4; ++r) {
      int row = qrow0 + quad * 4 + r;
      int col = h * 256 + g * 16 + lane15;
      attn_out[((size_t)b * S_LEN + row) * 2048 + col] = f2bf(o_acc[g][r] * linv[r]);
    }
  }
}

extern "C" void kernel_launch(void* const* d_in, const int* in_sizes, int n_in,
                              void* d_out, int out_size, void* d_ws, size_t ws_size,
                              hipStream_t stream) {
  const float* x = (const float*)d_in[0];
  const int* pos = (const int*)d_in[1];
  const float* wdq = (const float*)d_in[2];
  const float* bdq = (const float*)d_in[3];
  const float* qnw = (const float*)d_in[4];
  const float* wuq = (const float*)d_in[5];
  const float* buq = (const float*)d_in[6];
  const float* wdkv = (const float*)d_in[7];
  const float* bdkv = (const float*)d_in[8];
  const float* kvnw = (const float*)d_in[9];
  const float* wukv = (const float*)d_in[10];
  const float* bukv = (const float*)d_in[11];
  const float* wo = (const float*)d_in[12];
  const float* bo = (const float*)d_in[13];
  float* out = (float*)d_out;

  char* ws = (char*)d_ws;
  size_t off = 0;
  auto alloc = [&](size_t bytes) {
    char* p = ws + off;
    off += (bytes + 255) & ~(size_t)255;
    return p;
  };
  // vT (16.78MB) aliases xbf+t0+qout_spacer (22MB): all dead before k_gemm_qkv runs.
  // qout is no longer written (stageb fused) but KEPT as a spacer so the alias hole
  // stays >= vT size (removing it would shift wKVT into vT's range).
  u16* xbf = (u16*)alloc((size_t)R_TOK * 1024 * 2);    // dead after gemm A
  float* t0 = (float*)alloc((size_t)R_TOK * 320 * 4);  // dead after stagea
  u16* qout = (u16*)alloc((size_t)R_TOK * 1024 * 2);   // UNUSED spacer (alias hole)
  u16* vT = (u16*)d_ws;                                // alias of the three above
  u16* waT = (u16*)alloc((size_t)384 * 1024 * 2);      // padded 320->384 rows
  float* biasA = (float*)alloc(320 * 4);
  u16* wQT = (u16*)alloc((size_t)1024 * 128 * 2);
  u16* wKVT = (u16*)alloc((size_t)2560 * 128 * 2);
  u16* wOT = (u16*)alloc((size_t)1024 * 2048 * 2);
  u16* cq = (u16*)alloc((size_t)R_TOK * 128 * 2);
  u16* ckv = (u16*)alloc((size_t)R_TOK * 128 * 2);
  u16* krope = (u16*)alloc((size_t)R_TOK * 64 * 2);
  u16* qst = (u16*)alloc((size_t)R_TOK * 1024 * 2);
  u16* kvb = (u16*)alloc((size_t)R_TOK * 2560 * 2);
  u16* attnb = (u16*)alloc((size_t)R_TOK * 2048 * 2);
  float* qtab = (float*)alloc((size_t)R_TOK * 16 * 2 * 4);  // q-rope cos/sin table, 512KB
  (void)ws_size; (void)n_in; (void)in_sizes; (void)out_size; (void)qout;

  // prep part 1: x->bf16, waT, biasA (r12-exact)
  k_prep1<<<4417, 256, 0, stream>>>(x, xbf, wdq, wdkv, waT, bdq, bdkv, biasA);
  // gemm-A (96 blocks) + later-stage weight transposes (2496 blocks) in one launch
  k_gemma_wt<<<2592, 256, 0, stream>>>(xbf, waT, biasA, t0,
                                       wuq, wQT, wukv, wKVT, wo, wOT);
  k_stagea<<<R_TOK, 128, 0, stream>>>(t0, qnw, kvnw, pos, cq, ckv, krope, qtab);
  // fused q + kv up-projections (independent): 256 q-blocks + 640 kv-blocks, one launch
  k_gemm_qkv<<<896, 256, 0, stream>>>(cq, wQT, buq, qtab, qst, ckv, wKVT, bukv, kvb, vT);
  // attention: 256 blocks (1/CU, 96KB LDS, 8 waves = 2/SIMD), 512 threads (r3-exact)
  k_attn<<<dim3(16, 16), 512, 0, stream>>>(qst, kvb, krope, vT, attnb);
  // output projection -> fp32 out: 64x128 tile, 512 blocks = 2/CU = 2 waves/SIMD
  k_gemm_o<<<dim3(8, 64), 256, 0, stream>>>(attnb, wOT, bo, out);
}

// Round 16
// 240.400 us; speedup vs baseline: 1.1146x; 1.0139x over previous
//
#include <hip/hip_runtime.h>
#include <hip/hip_bf16.h>
#include <stdint.h>

typedef unsigned short u16;
typedef short short8 __attribute__((ext_vector_type(8)));
typedef float floatx4 __attribute__((ext_vector_type(4)));

#define S_LEN 2048
#define NB 2
#define NH 8
#define R_TOK (NB * S_LEN)  // 4096

#define L2_THETA 13.287712379549449f
// attention scale folded into Q, log2 domain: (1/sqrt(128)) * log2(e)
#define QSCALE (0.08838834764831845f * 1.4426950408889634f)

__device__ inline u16 f2bf(float f) {
  union { float f; uint32_t u; } x; x.f = f;
  uint32_t r = (x.u + 0x7fffu + ((x.u >> 16) & 1u)) >> 16;
  return (u16)r;
}
__device__ inline float bf2f(u16 h) {
  union { uint32_t u; float f; } x; x.u = ((uint32_t)h) << 16;
  return x.f;
}
__device__ inline floatx4 mfma16(short8 a, short8 b, floatx4 c) {
  return __builtin_amdgcn_mfma_f32_16x16x32_bf16(a, b, c, 0, 0, 0);
}
__device__ inline uint32_t pkbf(float a, float b) {
  union { __hip_bfloat162 h; uint32_t u; } c;
  c.h = __float22bfloat162_rn(make_float2(a, b));
  return c.u;
}
__device__ __forceinline__ void cp16(const void* g, const void* l) {
  __builtin_amdgcn_global_load_lds(
      (const __attribute__((address_space(1))) uint32_t*)(uintptr_t)g,
      (__attribute__((address_space(3))) uint32_t*)(uintptr_t)l, 16, 0, 0);
}

// ---------------- prep part 1 (r12-exact): x->bf16, waT transpose, biasA ----------------
__global__ __launch_bounds__(256) void k_prep1(
    const float* __restrict__ x, u16* __restrict__ xbf,
    const float* __restrict__ wdq, const float* __restrict__ wdkv, u16* __restrict__ waT,
    const float* __restrict__ bdq, const float* __restrict__ bdkv,
    float* __restrict__ biasA) {
  __shared__ u16 tile[32][33];
  const int s = blockIdx.x, tid = threadIdx.x;
  const int tx = tid & 31, ty = tid >> 5;
  if (s < 4096) {
    int i = s * 256 + tid;
    float4 v = ((const float4*)x)[i];
    ushort4 o;
    o.x = f2bf(v.x); o.y = f2bf(v.y); o.z = f2bf(v.z); o.w = f2bf(v.w);
    ((ushort4*)xbf)[i] = o;
  } else if (s < 4416) {  // waT: logical [1024][320] -> [320][1024]
    int t = s - 4096, bx = t % 10, by = t / 10;
    int c0 = bx * 32, r0 = by * 32;
#pragma unroll
    for (int i = 0; i < 4; ++i) {
      int r = r0 + ty + i * 8, c = c0 + tx;
      float v = (c < 128) ? wdq[(size_t)r * 128 + c] : wdkv[(size_t)r * 192 + (c - 128)];
      tile[ty + i * 8][tx] = f2bf(v);
    }
    __syncthreads();
#pragma unroll
    for (int i = 0; i < 4; ++i)
      waT[(size_t)(c0 + ty + i * 8) * 1024 + r0 + tx] = tile[tx][ty + i * 8];
  } else {
    if (tid < 320) biasA[tid] = (tid < 128) ? bdq[tid] : bdkv[tid - 128];
  }
}

// ------- gemm-A + weight-transpose uber-kernel (r16) -------
// Gemm path re-tiled 128x128 -> 64x128 (r15 mechanism: 1 wave/SIMD grid-capped latency
// exposure). 192 gemm blocks (64m x 3n) instead of 96: per-block work halves, critical
// path through the gemm shortens, transposes (blockIdx >= 192) still fill idle CUs.
// B over-reads rows 320..383 of waT are safe (padded to 384 rows); col<N guards output.
__global__ __launch_bounds__(256) void k_gemma_wt(
    const u16* __restrict__ A, const u16* __restrict__ BT,
    const float* __restrict__ bias, float* __restrict__ Cout,
    const float* __restrict__ wuq, u16* __restrict__ wQT,
    const float* __restrict__ wukv, u16* __restrict__ wKVT,
    const float* __restrict__ wo, u16* __restrict__ wOT) {
  const int tid = threadIdx.x;
  if (blockIdx.x >= 192) {  // ---- transpose path (block-uniform) ----
    __shared__ u16 tile[32][33];
    int t = blockIdx.x - 192;
    const float* in; u16* out; int R, C, bx, by;
    if (t < 128) { in = wuq; out = wQT; R = 128; C = 1024; bx = t & 31; by = t >> 5; }
    else if (t < 448) { int u = t - 128; in = wukv; out = wKVT; R = 128; C = 2560; bx = u % 80; by = u / 80; }
    else { int u = t - 448; in = wo; out = wOT; R = 2048; C = 1024; bx = u & 31; by = u >> 5; }
    const int tx = tid & 31, ty = tid >> 5;
    int c0 = bx * 32, r0 = by * 32;
#pragma unroll
    for (int i = 0; i < 4; ++i)
      tile[ty + i * 8][tx] = f2bf(in[(size_t)(r0 + ty + i * 8) * C + c0 + tx]);
    __syncthreads();
#pragma unroll
    for (int i = 0; i < 4; ++i)
      out[(size_t)(c0 + ty + i * 8) * R + r0 + tx] = tile[tx][ty + i * 8];
    return;
  }
  // ---- gemm path: M=4096, N=320, K=1024, fp32 out; 64x128 tile ----
  const int N = 320, K = 1024;
  __shared__ __align__(16) u16 Alds[2][64 * 32];    // 2 x 4 KB
  __shared__ __align__(16) u16 Blds[2][128 * 32];   // 2 x 8 KB
  const int wave = tid >> 6, lane = tid & 63;
  const int lane15 = lane & 15, quad = lane >> 4;
  const int n0 = (blockIdx.x % 3) * 128, m0 = (blockIdx.x / 3) * 64;

  floatx4 acc[4][2];
#pragma unroll
  for (int a = 0; a < 4; ++a)
#pragma unroll
    for (int b = 0; b < 2; ++b) acc[a][b] = (floatx4){0.f, 0.f, 0.f, 0.f};

  // A staging: 1 cp16/thread -> 64 rows x 32 cols
  const int arow = tid >> 2, acg = (tid & 3) * 8;
  // B staging: 2 cp16/thread: rows wave*32+(lane>>2) and +16
  const int srow = wave * 32 + (lane >> 2);
  const int scol = (lane & 3) * 8;
  auto stage = [&](int k0, int buf) {
    cp16(A + (size_t)(m0 + arow) * K + k0 + acg, Alds[buf] + arow * 32 + acg);
    const u16* gb = BT + (size_t)(n0 + srow) * K + k0 + scol;
    cp16(gb, Blds[buf] + srow * 32 + scol);
    cp16(gb + (size_t)16 * K, Blds[buf] + (srow + 16) * 32 + scol);
  };

  stage(0, 0);
  int cur = 0;
  for (int k0 = 0; k0 < K; k0 += 32) {
    __syncthreads();
    if (k0 + 32 < K) stage(k0 + 32, cur ^ 1);
    short8 af[4], bf[2];
#pragma unroll
    for (int im = 0; im < 4; ++im)
      af[im] = *(const short8*)&Alds[cur][(im * 16 + lane15) * 32 + quad * 8];
#pragma unroll
    for (int in = 0; in < 2; ++in)
      bf[in] = *(const short8*)&Blds[cur][(wave * 32 + in * 16 + lane15) * 32 + quad * 8];
#pragma unroll
    for (int im = 0; im < 4; ++im)
#pragma unroll
      for (int in = 0; in < 2; ++in) acc[im][in] = mfma16(af[im], bf[in], acc[im][in]);
    cur ^= 1;
  }

#pragma unroll
  for (int im = 0; im < 4; ++im)
#pragma unroll
    for (int in = 0; in < 2; ++in)
#pragma unroll
      for (int r = 0; r < 4; ++r) {
        int row = m0 + im * 16 + quad * 4 + r;
        int col = n0 + wave * 32 + in * 16 + lane15;
        if (col < N) Cout[(size_t)row * N + col] = acc[im][in][r] + bias[col];
      }
}

// ------- out-projection GEMM, 64x128 tile (r15-exact) -------
// attnb @ wOT + bo -> out fp32. M=4096, N=1024, K=2048. Grid (8,64) = 512 blocks =
// 2/CU = 2 waves/SIMD (fixed the 1-wave/SIMD latency exposure; -5us, r15).
__global__ __launch_bounds__(256) void k_gemm_o(const u16* __restrict__ A,
                                                const u16* __restrict__ BT,
                                                const float* __restrict__ bias,
                                                float* __restrict__ Cout) {
  const int N = 1024, K = 2048;
  __shared__ __align__(16) u16 Alds[2][64 * 32];    // 2 x 4 KB
  __shared__ __align__(16) u16 Blds[2][128 * 32];   // 2 x 8 KB
  const int tid = threadIdx.x;
  const int wave = tid >> 6, lane = tid & 63;
  const int lane15 = lane & 15, quad = lane >> 4;
  const int m0 = blockIdx.y * 64, n0 = blockIdx.x * 128;

  floatx4 acc[4][2];
#pragma unroll
  for (int a = 0; a < 4; ++a)
#pragma unroll
    for (int b = 0; b < 2; ++b) acc[a][b] = (floatx4){0.f, 0.f, 0.f, 0.f};

  // A staging: 1 cp16/thread -> 64 rows x 32 cols (row=tid>>2, colgroup=(tid&3)*8)
  const int arow = tid >> 2, acg = (tid & 3) * 8;
  // B staging: 2 cp16/thread: rows wave*32+(lane>>2) and +16
  const int srow = wave * 32 + (lane >> 2);
  const int scol = (lane & 3) * 8;
  auto stage = [&](int k0, int buf) {
    cp16(A + (size_t)(m0 + arow) * K + k0 + acg, Alds[buf] + arow * 32 + acg);
    const u16* gb = BT + (size_t)(n0 + srow) * K + k0 + scol;
    cp16(gb, Blds[buf] + srow * 32 + scol);
    cp16(gb + (size_t)16 * K, Blds[buf] + (srow + 16) * 32 + scol);
  };

  stage(0, 0);
  int cur = 0;
  for (int k0 = 0; k0 < K; k0 += 32) {
    __syncthreads();
    if (k0 + 32 < K) stage(k0 + 32, cur ^ 1);
    short8 af[4], bf[2];
#pragma unroll
    for (int im = 0; im < 4; ++im)
      af[im] = *(const short8*)&Alds[cur][(im * 16 + lane15) * 32 + quad * 8];
#pragma unroll
    for (int in = 0; in < 2; ++in)
      bf[in] = *(const short8*)&Blds[cur][(wave * 32 + in * 16 + lane15) * 32 + quad * 8];
#pragma unroll
    for (int im = 0; im < 4; ++im)
#pragma unroll
      for (int in = 0; in < 2; ++in) acc[im][in] = mfma16(af[im], bf[in], acc[im][in]);
    cur ^= 1;
  }

#pragma unroll
  for (int im = 0; im < 4; ++im)
#pragma unroll
    for (int in = 0; in < 2; ++in)
#pragma unroll
      for (int r = 0; r < 4; ++r) {
        int row = m0 + im * 16 + quad * 4 + r;
        int col = n0 + wave * 32 + in * 16 + lane15;
        Cout[(size_t)row * N + col] = acc[im][in][r] + bias[col];
      }
}

// ------- fused Q+KV GEMM uber-kernel (r10-exact) -------
__global__ __launch_bounds__(256) void k_gemm_qkv(
    const u16* __restrict__ Aq, const u16* __restrict__ BTq,
    const float* __restrict__ biasq, const float* __restrict__ qtab,
    u16* __restrict__ qstates,
    const u16* __restrict__ Akv, const u16* __restrict__ BTkv,
    const float* __restrict__ biaskv, u16* __restrict__ kvb, u16* __restrict__ vT) {
  const int K = 128;
  __shared__ __align__(16) u16 Alds[2][128 * 32];
  __shared__ __align__(16) u16 Blds[2][128 * 32];
  __shared__ __align__(16) u16 eplds[64 * 136];  // kv V-epilogue staging, 17.4 KB
  const int tid = threadIdx.x;
  const int wave = tid >> 6, lane = tid & 63;
  const int lane15 = lane & 15, quad = lane >> 4;
  const bool isq = blockIdx.x < 256;
  int m0, n0;
  const u16 *A, *BT;
  if (isq) {  // q: grid (32 m) x (8 n), m fastest
    int qb = blockIdx.x;
    m0 = (qb & 31) * 128;
    n0 = (qb >> 5) * 128;
    A = Aq; BT = BTq;
  } else {    // kv: grid (20 n) x (32 m), n fastest
    int kb = blockIdx.x - 256;
    n0 = (kb % 20) * 128;
    m0 = (kb / 20) * 128;
    A = Akv; BT = BTkv;
  }
  const int mw = (wave & 1) * 64, nw = (wave >> 1) * 64;

  floatx4 acc[4][4];
#pragma unroll
  for (int a = 0; a < 4; ++a)
#pragma unroll
    for (int b = 0; b < 4; ++b) acc[a][b] = (floatx4){0.f, 0.f, 0.f, 0.f};

  const int srow = wave * 32 + (lane >> 2);
  const int scol = (lane & 3) * 8;
  auto stage = [&](int k0, int buf) {
    const u16* ga = A + (size_t)(m0 + srow) * K + k0 + scol;
    cp16(ga, Alds[buf] + srow * 32 + scol);
    cp16(ga + (size_t)16 * K, Alds[buf] + (srow + 16) * 32 + scol);
    const u16* gb = BT + (size_t)(n0 + srow) * K + k0 + scol;
    cp16(gb, Blds[buf] + srow * 32 + scol);
    cp16(gb + (size_t)16 * K, Blds[buf] + (srow + 16) * 32 + scol);
  };

  stage(0, 0);
  int cur = 0;
  for (int k0 = 0; k0 < K; k0 += 32) {
    __syncthreads();
    if (k0 + 32 < K) stage(k0 + 32, cur ^ 1);
    short8 af[4], bf[4];
#pragma unroll
    for (int im = 0; im < 4; ++im)
      af[im] = *(const short8*)&Alds[cur][(mw + im * 16 + lane15) * 32 + quad * 8];
#pragma unroll
    for (int in = 0; in < 4; ++in)
      bf[in] = *(const short8*)&Blds[cur][(nw + in * 16 + lane15) * 32 + quad * 8];
#pragma unroll
    for (int im = 0; im < 4; ++im)
#pragma unroll
      for (int in = 0; in < 4; ++in) acc[im][in] = mfma16(af[im], bf[in], acc[im][in]);
    cur ^= 1;
  }

  if (isq) {  // ---- q epilogue: rope(table) + scale + scatter (r8-exact) ----
    const bool ropeblk = (n0 >= 768);
#pragma unroll
    for (int in = 0; in < 4; ++in) {
      const int col = n0 + nw + in * 16 + lane15;
#pragma unroll
      for (int im = 0; im < 4; ++im) {
        if (!ropeblk) {
          const int h = col / 96, d = col - h * 96;
#pragma unroll
          for (int r = 0; r < 4; ++r) {
            int row = m0 + mw + im * 16 + quad * 4 + r;
            int b = row >> 11, s = row & (S_LEN - 1);
            float v = acc[im][in][r] + biasq[col];
            qstates[((size_t)(b * NH + h) * S_LEN + s) * 128 + d] = f2bf(v * QSCALE);
          }
        } else {
          const int j = (col - 768) & 31, h = (col - 768) >> 5, pr = j >> 1;
#pragma unroll
          for (int r = 0; r < 4; ++r) {
            int row = m0 + mw + im * 16 + quad * 4 + r;
            int b = row >> 11, s = row & (S_LEN - 1);
            float v = acc[im][in][r] + biasq[col];
            float vp = __shfl_xor(v, 1);  // partner col^1 = lane15^1, same row
            float xe = (lane & 1) ? vp : v;
            float xo = (lane & 1) ? v : vp;
            float2 cs = *(const float2*)&qtab[((size_t)row * 16 + pr) * 2];  // (cos, sin)
            float val = (j & 1) ? (xe * cs.y + xo * cs.x) : (xe * cs.x - xo * cs.y);
            qstates[((size_t)(b * NH + h) * S_LEN + s) * 128 + 96 + j] = f2bf(val * QSCALE);
          }
        }
      }
    }
  } else if (n0 < 512) {  // ---- kv k_nope epilogue (r8-exact) ----
#pragma unroll
    for (int im = 0; im < 4; ++im)
#pragma unroll
      for (int in = 0; in < 4; ++in)
#pragma unroll
        for (int r = 0; r < 4; ++r) {
          int row = m0 + mw + im * 16 + quad * 4 + r;
          int col = n0 + nw + in * 16 + lane15;
          kvb[(size_t)row * 2560 + col] = f2bf(acc[im][in][r] + biaskv[col]);
        }
  } else {  // ---- kv V epilogue: two-pass LDS-staged coalesced vT write (r8-exact) ----
    const int sbase = m0 & (S_LEN - 1), bq = m0 >> 11;
#pragma unroll
    for (int hh = 0; hh < 2; ++hh) {
#pragma unroll
      for (int im = 0; im < 4; ++im) {
        const int rrel = mw + im * 16 + quad * 4;  // block-relative s, 0..127
        const int bb = (rrel & 63) >> 2;
        const int a = (bb & 8) | (((bb >> 1) & 1) << 2) | ((bb & 1) << 1) | ((bb >> 2) & 1);
        const int prel = (rrel >> 6) * 64 + a * 4;
#pragma unroll
        for (int ii = 0; ii < 2; ++ii) {
          const int in = hh * 2 + ii;
          const int nl = nw + in * 16 + lane15;
          const int slot = (nl & 31) | ((nl & 64) >> 1);
          const float bv = biaskv[n0 + nl];
          ushort4 o;
          o.x = f2bf(acc[im][in][0] + bv);
          o.y = f2bf(acc[im][in][1] + bv);
          o.z = f2bf(acc[im][in][2] + bv);
          o.w = f2bf(acc[im][in][3] + bv);
          *(ushort4*)&eplds[slot * 136 + prel] = o;
        }
      }
      __syncthreads();
#pragma unroll
      for (int i = 0; i < 4; ++i) {
        int idx = i * 256 + tid;
        int slot = idx >> 4, c8 = (idx & 15) * 8;
        int nl = (slot & 31) + hh * 32 + ((slot & 32) << 1);
        int c2 = n0 + nl - 512;
        int hv = c2 >> 8, nn = c2 & 255;
        short8 v = *(const short8*)&eplds[slot * 136 + c8];
        *(short8*)&vT[((size_t)((bq * NH + hv) * 256 + nn)) * 2048 + sbase + c8] = v;
      }
      if (hh == 0) __syncthreads();
    }
  }
}

// ------- stage-A epilogue: rmsnorm(cq), rmsnorm(ckv), rope(k_rope), q-rope table -------
__global__ void k_stagea(const float* __restrict__ t0, const float* __restrict__ qnw,
                         const float* __restrict__ kvnw, const int* __restrict__ pos_ids,
                         u16* __restrict__ cq, u16* __restrict__ ckv,
                         u16* __restrict__ krope, float* __restrict__ qtab) {
  int r = blockIdx.x, tid = threadIdx.x;  // 128 threads
  const float* row = t0 + (size_t)r * 320;
  float a = row[tid];
  float b = row[128 + tid];
  float sa = a * a, sb = b * b;
#pragma unroll
  for (int d = 1; d < 64; d <<= 1) {
    sa += __shfl_xor(sa, d);
    sb += __shfl_xor(sb, d);
  }
  __shared__ float red[4];
  if ((tid & 63) == 0) { red[(tid >> 6) * 2] = sa; red[(tid >> 6) * 2 + 1] = sb; }
  __syncthreads();
  sa = red[0] + red[2];
  sb = red[1] + red[3];
  float ra = rsqrtf(sa * (1.0f / 128.0f) + 1e-8f);
  float rb = rsqrtf(sb * (1.0f / 128.0f) + 1e-8f);
  cq[(size_t)r * 128 + tid] = f2bf(qnw[tid] * a * ra);
  ckv[(size_t)r * 128 + tid] = f2bf(kvnw[tid] * b * rb);
  if (tid < 32) {
    float xe = row[256 + 2 * tid], xo = row[256 + 2 * tid + 1];
    float p = (float)pos_ids[r];
    float freq = exp2f(-(2.0f * tid / 64.0f) * L2_THETA);
    float ang = p * freq;
    float c = cosf(ang), s = sinf(ang);
    krope[(size_t)r * 64 + 2 * tid] = f2bf(xe * c - xo * s);
    krope[(size_t)r * 64 + 2 * tid + 1] = f2bf(xe * s + xo * c);
  } else if (tid < 48) {
    // q-rope table: bitwise-identical formula to the old k_stageb path
    int pr = tid - 32;
    float p = (float)pos_ids[r];
    float freq = exp2f(-(2.0f * pr / 32.0f) * L2_THETA);
    float ang = p * freq;
    qtab[((size_t)r * 16 + pr) * 2] = cosf(ang);
    qtab[((size_t)r * 16 + pr) * 2 + 1] = sinf(ang);
  }
}

// ---------------- flash attention: 2-phase double-buffered pipeline (r3-exact) ----------
// Best-known attn: 88.1-90.5us, reproduced 9x. All deviations regressed: r5 n-split
// (+26%), r9 q-split (+17%, 1 wave/SIMD), r11 V-frag hoist (+2.5us, schedule
// perturbation). This structure is the banked floor -- do not edit.
__global__ __launch_bounds__(512) void k_attn(const u16* __restrict__ qstates,
                                              const u16* __restrict__ kv,
                                              const u16* __restrict__ krope,
                                              const u16* __restrict__ vT,
                                              u16* __restrict__ attn_out) {
  const int pair = blockIdx.x;  // 0..15 (pair-major: XCD = pair%8)
  const int qblk = blockIdx.y;  // 0..15
  const int b = pair >> 3, h = pair & 7;
  const int tid = threadIdx.x;
  const int wave = tid >> 6, lane = tid & 63;
  const int lane15 = lane & 15, quad = lane >> 4;
  const int w4 = wave & 3, half = wave >> 2;

  __shared__ __align__(16) u16 Klds[2][64 * 128];   // 2 x 16 KB
  __shared__ __align__(16) u16 Vlds[2][256 * 64];   // 2 x 32 KB

  const int qrow0 = qblk * 128 + wave * 16;
  short8 qfrag[4];
  {
    const u16* qb = qstates + ((size_t)(b * NH + h) * S_LEN + qrow0 + lane15) * 128 + quad * 8;
#pragma unroll
    for (int c = 0; c < 4; ++c) qfrag[c] = *(const short8*)(qb + c * 32);
  }

  floatx4 o_acc[16];
#pragma unroll
  for (int g = 0; g < 16; ++g) o_acc[g] = (floatx4){0.f, 0.f, 0.f, 0.f};
  float m_i = -1e30f;
  float l_i = 0.f;  // per-lane PARTIAL row-sum; reduced at epilogue

  // ---- hoisted, ch-invariant LDS read offsets (u16 units) ----
  const int kbase = (quad * 16 + lane15) * 8;  // + (t*16+c*4)*128 (imm)
  int vo0[4], vo1[4];
#pragma unroll
  for (int ph = 0; ph < 4; ++ph) {
    int n = ph * 16 + lane15;
    int sw = (n ^ (n >> 3)) & 7;
    vo0[ph] = n * 64 + ((quad ^ sw) & 7) * 8;
    vo1[ph] = n * 64 + (((quad | 4) ^ sw) & 7) * 8;
  }

  // K staging (512 thr, 2 cp16/thread): row = w4*16+lane15, unit u = half*8 + 4j + quad.
  const u16* kp[2];
  int kstr[2];
  int kdst[2];
#pragma unroll
  for (int j = 0; j < 2; ++j) {
    int u = half * 8 + j * 4 + quad;
    const u16* base;
    int str;
    if (u < 8) { base = kv + h * 64 + u * 8; str = 2560; }
    else { base = krope + (u - 8) * 8; str = 64; }
    kp[j] = base + (size_t)(b * S_LEN + w4 * 16 + lane15) * str;
    kstr[j] = str;
    kdst[j] = (w4 * 256 + (half * 2 + j) * 64 + lane) * 8;
  }
  // V staging (512 thr, 4 cp16/thread): n = oi*64 + (tid>>3), slot = tid&7
  const int vn6 = tid >> 3, vsl = tid & 7;
  const u16* vp[4];
#pragma unroll
  for (int oi = 0; oi < 4; ++oi) {
    int n = oi * 64 + vn6;
    int u = vsl ^ ((n ^ (n >> 3)) & 7);
    vp[oi] = vT + ((size_t)pair * 256 + n) * 2048 + u * 8;
  }

  auto issueK = [&](int buf) {
#pragma unroll
    for (int j = 0; j < 2; ++j) {
      cp16(kp[j], &Klds[buf][kdst[j]]);
      kp[j] += (size_t)64 * kstr[j];
    }
  };
  auto issueV = [&](int buf) {
#pragma unroll
    for (int oi = 0; oi < 4; ++oi) {
      cp16(vp[oi], &Vlds[buf][(oi * 512 + tid) * 8]);
      vp[oi] += 64;
    }
  };

  // prologue: fill buf0, drain, converge
  issueK(0);
  issueV(0);
  asm volatile("s_waitcnt vmcnt(0)" ::: "memory");
  __builtin_amdgcn_sched_barrier(0);
  __builtin_amdgcn_s_barrier();

  int cur = 0;
  for (int ch = 0; ch < S_LEN / 64; ++ch) {
    if (ch + 1 < S_LEN / 64) {
      issueK(cur ^ 1);
      issueV(cur ^ 1);
    }

    // S^T = K * Q^T : st[t][r] = S[q=lane15][k = t*16 + quad*4 + r] (log2 domain)
    floatx4 st[4];
#pragma unroll
    for (int t = 0; t < 4; ++t) st[t] = (floatx4){0.f, 0.f, 0.f, 0.f};
    __builtin_amdgcn_s_setprio(1);
#pragma unroll
    for (int c = 0; c < 4; ++c) {
      short8 qf = qfrag[c];
#pragma unroll
      for (int t = 0; t < 4; ++t) {
        short8 kf = *(const short8*)&Klds[cur][kbase + (t * 16 + c * 4) * 128];
        st[t] = mfma16(kf, qf, st[t]);
      }
    }
    __builtin_amdgcn_s_setprio(0);

    // row max: fmax tree + 2-shfl butterfly (l-sum reduce deferred to epilogue)
    float mloc = st[0][0];
#pragma unroll
    for (int t = 0; t < 4; ++t)
#pragma unroll
      for (int r = 0; r < 4; ++r) mloc = fmaxf(mloc, st[t][r]);
    mloc = fmaxf(mloc, __shfl_xor(mloc, 16));
    mloc = fmaxf(mloc, __shfl_xor(mloc, 32));

    // defer-max: only rescale when max grew by >8 (log2 domain); P bounded by 2^8
    const bool resc = __any(mloc > m_i + 8.0f);
    const float mref = resc ? fmaxf(m_i, mloc) : m_i;

    float rs = 0.f;
    union { short8 s; uint4 u; } a01, a23;
    {
      float p0, p1, p2, p3;
      p0 = exp2f(st[0][0] - mref); p1 = exp2f(st[0][1] - mref);
      p2 = exp2f(st[0][2] - mref); p3 = exp2f(st[0][3] - mref);
      rs += (p0 + p1) + (p2 + p3);
      a01.u.x = pkbf(p0, p1); a01.u.y = pkbf(p2, p3);
      p0 = exp2f(st[1][0] - mref); p1 = exp2f(st[1][1] - mref);
      p2 = exp2f(st[1][2] - mref); p3 = exp2f(st[1][3] - mref);
      rs += (p0 + p1) + (p2 + p3);
      a01.u.z = pkbf(p0, p1); a01.u.w = pkbf(p2, p3);
      p0 = exp2f(st[2][0] - mref); p1 = exp2f(st[2][1] - mref);
      p2 = exp2f(st[2][2] - mref); p3 = exp2f(st[2][3] - mref);
      rs += (p0 + p1) + (p2 + p3);
      a23.u.x = pkbf(p0, p1); a23.u.y = pkbf(p2, p3);
      p0 = exp2f(st[3][0] - mref); p1 = exp2f(st[3][1] - mref);
      p2 = exp2f(st[3][2] - mref); p3 = exp2f(st[3][3] - mref);
      rs += (p0 + p1) + (p2 + p3);
      a23.u.z = pkbf(p0, p1); a23.u.w = pkbf(p2, p3);
    }

    if (resc) {  // rare after chunk 0 (THR=8): alpha rescale of o_acc + l_i
      float alpha = exp2f(m_i - mref);
      m_i = mref;
      l_i = l_i * alpha + rs;
      float al[4];
#pragma unroll
      for (int r = 0; r < 4; ++r) al[r] = __shfl(alpha, quad * 4 + r, 16);
#pragma unroll
      for (int g = 0; g < 16; ++g) {
        o_acc[g][0] *= al[0]; o_acc[g][1] *= al[1];
        o_acc[g][2] *= al[2]; o_acc[g][3] *= al[3];
      }
    } else {
      l_i += rs;
    }

    // PV: b-frags are single b128 reads (permuted-k vT layout, hoisted bases)
    __builtin_amdgcn_s_setprio(1);
#pragma unroll
    for (int g = 0; g < 16; ++g) {
      short8 b01 = *(const short8*)&Vlds[cur][vo0[g & 3] + (g >> 2) * 4096];
      short8 b23 = *(const short8*)&Vlds[cur][vo1[g & 3] + (g >> 2) * 4096];
      floatx4 o = o_acc[g];
      o = mfma16(a01.s, b01, o);
      o = mfma16(a23.s, b23, o);
      o_acc[g] = o;
    }
    __builtin_amdgcn_s_setprio(0);

    // single per-chunk sync: next-chunk loads had all of compute to land;
    // barrier seals this chunk's LDS reads before buf[cur] is overwritten.
    asm volatile("s_waitcnt vmcnt(0)" ::: "memory");
    __builtin_amdgcn_sched_barrier(0);
    __builtin_amdgcn_s_barrier();
    cur ^= 1;
  }

  // epilogue: reduce the per-quad partial row-sums once, then normalize
  float lsum = l_i;
  lsum += __shfl_xor(lsum, 16);
  lsum += __shfl_xor(lsum, 32);
  float rl = 1.0f / lsum;
  float linv[4];
#pragma unroll
  for (int r = 0; r < 4; ++r) linv[r] = __shfl(rl, quad * 4 + r, 16);
#pragma unroll
  for (int g = 0; g < 16; ++g) {
#pragma unroll
    for (int r = 0; r < 4; ++r) {
      int row = qrow0 + quad * 4 + r;
      int col = h * 256 + g * 16 + lane15;
      attn_out[((size_t)b * S_LEN + row) * 2048 + col] = f2bf(o_acc[g][r] * linv[r]);
    }
  }
}

extern "C" void kernel_launch(void* const* d_in, const int* in_sizes, int n_in,
                              void* d_out, int out_size, void* d_ws, size_t ws_size,
                              hipStream_t stream) {
  const float* x = (const float*)d_in[0];
  const int* pos = (const int*)d_in[1];
  const float* wdq = (const float*)d_in[2];
  const float* bdq = (const float*)d_in[3];
  const float* qnw = (const float*)d_in[4];
  const float* wuq = (const float*)d_in[5];
  const float* buq = (const float*)d_in[6];
  const float* wdkv = (const float*)d_in[7];
  const float* bdkv = (const float*)d_in[8];
  const float* kvnw = (const float*)d_in[9];
  const float* wukv = (const float*)d_in[10];
  const float* bukv = (const float*)d_in[11];
  const float* wo = (const float*)d_in[12];
  const float* bo = (const float*)d_in[13];
  float* out = (float*)d_out;

  char* ws = (char*)d_ws;
  size_t off = 0;
  auto alloc = [&](size_t bytes) {
    char* p = ws + off;
    off += (bytes + 255) & ~(size_t)255;
    return p;
  };
  // vT (16.78MB) aliases xbf+t0+qout_spacer (22MB): all dead before k_gemm_qkv runs.
  // qout is no longer written (stageb fused) but KEPT as a spacer so the alias hole
  // stays >= vT size (removing it would shift wKVT into vT's range).
  u16* xbf = (u16*)alloc((size_t)R_TOK * 1024 * 2);    // dead after gemm A
  float* t0 = (float*)alloc((size_t)R_TOK * 320 * 4);  // dead after stagea
  u16* qout = (u16*)alloc((size_t)R_TOK * 1024 * 2);   // UNUSED spacer (alias hole)
  u16* vT = (u16*)d_ws;                                // alias of the three above
  u16* waT = (u16*)alloc((size_t)384 * 1024 * 2);      // padded 320->384 rows
  float* biasA = (float*)alloc(320 * 4);
  u16* wQT = (u16*)alloc((size_t)1024 * 128 * 2);
  u16* wKVT = (u16*)alloc((size_t)2560 * 128 * 2);
  u16* wOT = (u16*)alloc((size_t)1024 * 2048 * 2);
  u16* cq = (u16*)alloc((size_t)R_TOK * 128 * 2);
  u16* ckv = (u16*)alloc((size_t)R_TOK * 128 * 2);
  u16* krope = (u16*)alloc((size_t)R_TOK * 64 * 2);
  u16* qst = (u16*)alloc((size_t)R_TOK * 1024 * 2);
  u16* kvb = (u16*)alloc((size_t)R_TOK * 2560 * 2);
  u16* attnb = (u16*)alloc((size_t)R_TOK * 2048 * 2);
  float* qtab = (float*)alloc((size_t)R_TOK * 16 * 2 * 4);  // q-rope cos/sin table, 512KB
  (void)ws_size; (void)n_in; (void)in_sizes; (void)out_size; (void)qout;

  // prep part 1: x->bf16, waT, biasA (r12-exact)
  k_prep1<<<4417, 256, 0, stream>>>(x, xbf, wdq, wdkv, waT, bdq, bdkv, biasA);
  // gemm-A (192 blocks, 64x128 tile) + later-stage weight transposes (2496 blocks)
  k_gemma_wt<<<2688, 256, 0, stream>>>(xbf, waT, biasA, t0,
                                       wuq, wQT, wukv, wKVT, wo, wOT);
  k_stagea<<<R_TOK, 128, 0, stream>>>(t0, qnw, kvnw, pos, cq, ckv, krope, qtab);
  // fused q + kv up-projections (independent): 256 q-blocks + 640 kv-blocks, one launch
  k_gemm_qkv<<<896, 256, 0, stream>>>(cq, wQT, buq, qtab, qst, ckv, wKVT, bukv, kvb, vT);
  // attention: 256 blocks (1/CU, 96KB LDS, 8 waves = 2/SIMD), 512 threads (r3-exact)
  k_attn<<<dim3(16, 16), 512, 0, stream>>>(qst, kvb, krope, vT, attnb);
  // output projection -> fp32 out: 64x128 tile, 512 blocks = 2/CU = 2 waves/SIMD
  k_gemm_o<<<dim3(8, 64), 256, 0, stream>>>(attnb, wOT, bo, out);
}

// Round 18
// 237.723 us; speedup vs baseline: 1.1272x; 1.0113x over previous
//
#include <hip/hip_runtime.h>
#include <hip/hip_bf16.h>
#include <stdint.h>

typedef unsigned short u16;
typedef short short8 __attribute__((ext_vector_type(8)));
typedef float floatx4 __attribute__((ext_vector_type(4)));

#define S_LEN 2048
#define NB 2
#define NH 8
#define R_TOK (NB * S_LEN)  // 4096

#define L2_THETA 13.287712379549449f
// attention scale folded into Q, log2 domain: (1/sqrt(128)) * log2(e)
#define QSCALE (0.08838834764831845f * 1.4426950408889634f)

__device__ inline u16 f2bf(float f) {
  union { float f; uint32_t u; } x; x.f = f;
  uint32_t r = (x.u + 0x7fffu + ((x.u >> 16) & 1u)) >> 16;
  return (u16)r;
}
__device__ inline float bf2f(u16 h) {
  union { uint32_t u; float f; } x; x.u = ((uint32_t)h) << 16;
  return x.f;
}
__device__ inline floatx4 mfma16(short8 a, short8 b, floatx4 c) {
  return __builtin_amdgcn_mfma_f32_16x16x32_bf16(a, b, c, 0, 0, 0);
}
__device__ inline uint32_t pkbf(float a, float b) {
  union { __hip_bfloat162 h; uint32_t u; } c;
  c.h = __float22bfloat162_rn(make_float2(a, b));
  return c.u;
}
__device__ __forceinline__ void cp16(const void* g, const void* l) {
  __builtin_amdgcn_global_load_lds(
      (const __attribute__((address_space(1))) uint32_t*)(uintptr_t)g,
      (__attribute__((address_space(3))) uint32_t*)(uintptr_t)l, 16, 0, 0);
}

// ---------------- prep part 1 (r12-exact): x->bf16, waT transpose, biasA ----------------
__global__ __launch_bounds__(256) void k_prep1(
    const float* __restrict__ x, u16* __restrict__ xbf,
    const float* __restrict__ wdq, const float* __restrict__ wdkv, u16* __restrict__ waT,
    const float* __restrict__ bdq, const float* __restrict__ bdkv,
    float* __restrict__ biasA) {
  __shared__ u16 tile[32][33];
  const int s = blockIdx.x, tid = threadIdx.x;
  const int tx = tid & 31, ty = tid >> 5;
  if (s < 4096) {
    int i = s * 256 + tid;
    float4 v = ((const float4*)x)[i];
    ushort4 o;
    o.x = f2bf(v.x); o.y = f2bf(v.y); o.z = f2bf(v.z); o.w = f2bf(v.w);
    ((ushort4*)xbf)[i] = o;
  } else if (s < 4416) {  // waT: logical [1024][320] -> [320][1024]
    int t = s - 4096, bx = t % 10, by = t / 10;
    int c0 = bx * 32, r0 = by * 32;
#pragma unroll
    for (int i = 0; i < 4; ++i) {
      int r = r0 + ty + i * 8, c = c0 + tx;
      float v = (c < 128) ? wdq[(size_t)r * 128 + c] : wdkv[(size_t)r * 192 + (c - 128)];
      tile[ty + i * 8][tx] = f2bf(v);
    }
    __syncthreads();
#pragma unroll
    for (int i = 0; i < 4; ++i)
      waT[(size_t)(c0 + ty + i * 8) * 1024 + r0 + tx] = tile[tx][ty + i * 8];
  } else {
    if (tid < 320) biasA[tid] = (tid < 128) ? bdq[tid] : bdkv[tid - 128];
  }
}

// ------- gemm-A + weight-transpose uber-kernel (r18: BK=64, lane-linear staging) -------
// r17 NaN post-mortem: global_load_lds writes LDS at wave-uniform base + lane*16B (guide
// rule #21); r17's maps put lane l at l*32B / l*64B -> HW scattered garbage. r18 maps are
// lane-linear for the 64-col stride: row=tid>>3, col=(tid&7)*8 -> within-wave offset
// (l>>3)*64+(l&7)*8 = l*8 u16 = l*16B. BK=64 mechanism kept: 16 MFMA/barrier, barriers
// 32 -> 16. Accumulation order unchanged (kk=0 then 32) -> bitwise-identical output.
__global__ __launch_bounds__(256) void k_gemma_wt(
    const u16* __restrict__ A, const u16* __restrict__ BT,
    const float* __restrict__ bias, float* __restrict__ Cout,
    const float* __restrict__ wuq, u16* __restrict__ wQT,
    const float* __restrict__ wukv, u16* __restrict__ wKVT,
    const float* __restrict__ wo, u16* __restrict__ wOT) {
  const int tid = threadIdx.x;
  if (blockIdx.x >= 192) {  // ---- transpose path (block-uniform) ----
    __shared__ u16 tile[32][33];
    int t = blockIdx.x - 192;
    const float* in; u16* out; int R, C, bx, by;
    if (t < 128) { in = wuq; out = wQT; R = 128; C = 1024; bx = t & 31; by = t >> 5; }
    else if (t < 448) { int u = t - 128; in = wukv; out = wKVT; R = 128; C = 2560; bx = u % 80; by = u / 80; }
    else { int u = t - 448; in = wo; out = wOT; R = 2048; C = 1024; bx = u & 31; by = u >> 5; }
    const int tx = tid & 31, ty = tid >> 5;
    int c0 = bx * 32, r0 = by * 32;
#pragma unroll
    for (int i = 0; i < 4; ++i)
      tile[ty + i * 8][tx] = f2bf(in[(size_t)(r0 + ty + i * 8) * C + c0 + tx]);
    __syncthreads();
#pragma unroll
    for (int i = 0; i < 4; ++i)
      out[(size_t)(c0 + ty + i * 8) * R + r0 + tx] = tile[tx][ty + i * 8];
    return;
  }
  // ---- gemm path: M=4096, N=320, K=1024, fp32 out; 64x128 tile, BK=64 ----
  const int N = 320, K = 1024;
  __shared__ __align__(16) u16 Alds[2][64 * 64];    // 2 x 8 KB
  __shared__ __align__(16) u16 Blds[2][128 * 64];   // 2 x 16 KB
  const int wave = tid >> 6, lane = tid & 63;
  const int lane15 = lane & 15, quad = lane >> 4;
  const int n0 = (blockIdx.x % 3) * 128, m0 = (blockIdx.x / 3) * 64;

  floatx4 acc[4][2];
#pragma unroll
  for (int a = 0; a < 4; ++a)
#pragma unroll
    for (int b = 0; b < 2; ++b) acc[a][b] = (floatx4){0.f, 0.f, 0.f, 0.f};

  // lane-linear staging for 64-col stride: row=tid>>3 (0..31), col=(tid&7)*8
  const int srow = tid >> 3, scol8 = (tid & 7) * 8;
  auto stage = [&](int k0, int buf) {
    // A: 64 rows x 64 cols, rows srow and srow+32
    const u16* ga = A + (size_t)(m0 + srow) * K + k0 + scol8;
    cp16(ga, Alds[buf] + srow * 64 + scol8);
    cp16(ga + (size_t)32 * K, Alds[buf] + (srow + 32) * 64 + scol8);
    // B: 128 rows x 64 cols, rows srow + 32j
    const u16* gb = BT + (size_t)(n0 + srow) * K + k0 + scol8;
#pragma unroll
    for (int j = 0; j < 4; ++j)
      cp16(gb + (size_t)(32 * j) * K, Blds[buf] + (srow + 32 * j) * 64 + scol8);
  };

  stage(0, 0);
  int cur = 0;
  for (int k0 = 0; k0 < K; k0 += 64) {
    __syncthreads();
    if (k0 + 64 < K) stage(k0 + 64, cur ^ 1);
#pragma unroll
    for (int kk = 0; kk < 64; kk += 32) {
      short8 af[4], bf[2];
#pragma unroll
      for (int im = 0; im < 4; ++im)
        af[im] = *(const short8*)&Alds[cur][(im * 16 + lane15) * 64 + kk + quad * 8];
#pragma unroll
      for (int in = 0; in < 2; ++in)
        bf[in] = *(const short8*)&Blds[cur][(wave * 32 + in * 16 + lane15) * 64 + kk + quad * 8];
#pragma unroll
      for (int im = 0; im < 4; ++im)
#pragma unroll
        for (int in = 0; in < 2; ++in) acc[im][in] = mfma16(af[im], bf[in], acc[im][in]);
    }
    cur ^= 1;
  }

#pragma unroll
  for (int im = 0; im < 4; ++im)
#pragma unroll
    for (int in = 0; in < 2; ++in)
#pragma unroll
      for (int r = 0; r < 4; ++r) {
        int row = m0 + im * 16 + quad * 4 + r;
        int col = n0 + wave * 32 + in * 16 + lane15;
        if (col < N) Cout[(size_t)row * N + col] = acc[im][in][r] + bias[col];
      }
}

// ------- out-projection GEMM, 64x128 tile, BK=64, lane-linear staging (r18) -------
// attnb @ wOT + bo -> out fp32. M=4096, N=1024, K=2048. Grid (8,64) = 512 = 2/CU.
// BK=64: 16 MFMA/barrier, barriers 64 -> 32. LDS 48KB (2 blocks/CU at grid 512).
__global__ __launch_bounds__(256) void k_gemm_o(const u16* __restrict__ A,
                                                const u16* __restrict__ BT,
                                                const float* __restrict__ bias,
                                                float* __restrict__ Cout) {
  const int N = 1024, K = 2048;
  __shared__ __align__(16) u16 Alds[2][64 * 64];    // 2 x 8 KB
  __shared__ __align__(16) u16 Blds[2][128 * 64];   // 2 x 16 KB
  const int tid = threadIdx.x;
  const int wave = tid >> 6, lane = tid & 63;
  const int lane15 = lane & 15, quad = lane >> 4;
  const int m0 = blockIdx.y * 64, n0 = blockIdx.x * 128;

  floatx4 acc[4][2];
#pragma unroll
  for (int a = 0; a < 4; ++a)
#pragma unroll
    for (int b = 0; b < 2; ++b) acc[a][b] = (floatx4){0.f, 0.f, 0.f, 0.f};

  // lane-linear staging for 64-col stride: row=tid>>3 (0..31), col=(tid&7)*8
  const int srow = tid >> 3, scol8 = (tid & 7) * 8;
  auto stage = [&](int k0, int buf) {
    const u16* ga = A + (size_t)(m0 + srow) * K + k0 + scol8;
    cp16(ga, Alds[buf] + srow * 64 + scol8);
    cp16(ga + (size_t)32 * K, Alds[buf] + (srow + 32) * 64 + scol8);
    const u16* gb = BT + (size_t)(n0 + srow) * K + k0 + scol8;
#pragma unroll
    for (int j = 0; j < 4; ++j)
      cp16(gb + (size_t)(32 * j) * K, Blds[buf] + (srow + 32 * j) * 64 + scol8);
  };

  stage(0, 0);
  int cur = 0;
  for (int k0 = 0; k0 < K; k0 += 64) {
    __syncthreads();
    if (k0 + 64 < K) stage(k0 + 64, cur ^ 1);
#pragma unroll
    for (int kk = 0; kk < 64; kk += 32) {
      short8 af[4], bf[2];
#pragma unroll
      for (int im = 0; im < 4; ++im)
        af[im] = *(const short8*)&Alds[cur][(im * 16 + lane15) * 64 + kk + quad * 8];
#pragma unroll
      for (int in = 0; in < 2; ++in)
        bf[in] = *(const short8*)&Blds[cur][(wave * 32 + in * 16 + lane15) * 64 + kk + quad * 8];
#pragma unroll
      for (int im = 0; im < 4; ++im)
#pragma unroll
        for (int in = 0; in < 2; ++in) acc[im][in] = mfma16(af[im], bf[in], acc[im][in]);
    }
    cur ^= 1;
  }

#pragma unroll
  for (int im = 0; im < 4; ++im)
#pragma unroll
    for (int in = 0; in < 2; ++in)
#pragma unroll
      for (int r = 0; r < 4; ++r) {
        int row = m0 + im * 16 + quad * 4 + r;
        int col = n0 + wave * 32 + in * 16 + lane15;
        Cout[(size_t)row * N + col] = acc[im][in][r] + bias[col];
      }
}

// ------- fused Q+KV GEMM uber-kernel (r10-exact) -------
__global__ __launch_bounds__(256) void k_gemm_qkv(
    const u16* __restrict__ Aq, const u16* __restrict__ BTq,
    const float* __restrict__ biasq, const float* __restrict__ qtab,
    u16* __restrict__ qstates,
    const u16* __restrict__ Akv, const u16* __restrict__ BTkv,
    const float* __restrict__ biaskv, u16* __restrict__ kvb, u16* __restrict__ vT) {
  const int K = 128;
  __shared__ __align__(16) u16 Alds[2][128 * 32];
  __shared__ __align__(16) u16 Blds[2][128 * 32];
  __shared__ __align__(16) u16 eplds[64 * 136];  // kv V-epilogue staging, 17.4 KB
  const int tid = threadIdx.x;
  const int wave = tid >> 6, lane = tid & 63;
  const int lane15 = lane & 15, quad = lane >> 4;
  const bool isq = blockIdx.x < 256;
  int m0, n0;
  const u16 *A, *BT;
  if (isq) {  // q: grid (32 m) x (8 n), m fastest
    int qb = blockIdx.x;
    m0 = (qb & 31) * 128;
    n0 = (qb >> 5) * 128;
    A = Aq; BT = BTq;
  } else {    // kv: grid (20 n) x (32 m), n fastest
    int kb = blockIdx.x - 256;
    n0 = (kb % 20) * 128;
    m0 = (kb / 20) * 128;
    A = Akv; BT = BTkv;
  }
  const int mw = (wave & 1) * 64, nw = (wave >> 1) * 64;

  floatx4 acc[4][4];
#pragma unroll
  for (int a = 0; a < 4; ++a)
#pragma unroll
    for (int b = 0; b < 4; ++b) acc[a][b] = (floatx4){0.f, 0.f, 0.f, 0.f};

  const int srow = wave * 32 + (lane >> 2);
  const int scol = (lane & 3) * 8;
  auto stage = [&](int k0, int buf) {
    const u16* ga = A + (size_t)(m0 + srow) * K + k0 + scol;
    cp16(ga, Alds[buf] + srow * 32 + scol);
    cp16(ga + (size_t)16 * K, Alds[buf] + (srow + 16) * 32 + scol);
    const u16* gb = BT + (size_t)(n0 + srow) * K + k0 + scol;
    cp16(gb, Blds[buf] + srow * 32 + scol);
    cp16(gb + (size_t)16 * K, Blds[buf] + (srow + 16) * 32 + scol);
  };

  stage(0, 0);
  int cur = 0;
  for (int k0 = 0; k0 < K; k0 += 32) {
    __syncthreads();
    if (k0 + 32 < K) stage(k0 + 32, cur ^ 1);
    short8 af[4], bf[4];
#pragma unroll
    for (int im = 0; im < 4; ++im)
      af[im] = *(const short8*)&Alds[cur][(mw + im * 16 + lane15) * 32 + quad * 8];
#pragma unroll
    for (int in = 0; in < 4; ++in)
      bf[in] = *(const short8*)&Blds[cur][(nw + in * 16 + lane15) * 32 + quad * 8];
#pragma unroll
    for (int im = 0; im < 4; ++im)
#pragma unroll
      for (int in = 0; in < 4; ++in) acc[im][in] = mfma16(af[im], bf[in], acc[im][in]);
    cur ^= 1;
  }

  if (isq) {  // ---- q epilogue: rope(table) + scale + scatter (r8-exact) ----
    const bool ropeblk = (n0 >= 768);
#pragma unroll
    for (int in = 0; in < 4; ++in) {
      const int col = n0 + nw + in * 16 + lane15;
#pragma unroll
      for (int im = 0; im < 4; ++im) {
        if (!ropeblk) {
          const int h = col / 96, d = col - h * 96;
#pragma unroll
          for (int r = 0; r < 4; ++r) {
            int row = m0 + mw + im * 16 + quad * 4 + r;
            int b = row >> 11, s = row & (S_LEN - 1);
            float v = acc[im][in][r] + biasq[col];
            qstates[((size_t)(b * NH + h) * S_LEN + s) * 128 + d] = f2bf(v * QSCALE);
          }
        } else {
          const int j = (col - 768) & 31, h = (col - 768) >> 5, pr = j >> 1;
#pragma unroll
          for (int r = 0; r < 4; ++r) {
            int row = m0 + mw + im * 16 + quad * 4 + r;
            int b = row >> 11, s = row & (S_LEN - 1);
            float v = acc[im][in][r] + biasq[col];
            float vp = __shfl_xor(v, 1);  // partner col^1 = lane15^1, same row
            float xe = (lane & 1) ? vp : v;
            float xo = (lane & 1) ? v : vp;
            float2 cs = *(const float2*)&qtab[((size_t)row * 16 + pr) * 2];  // (cos, sin)
            float val = (j & 1) ? (xe * cs.y + xo * cs.x) : (xe * cs.x - xo * cs.y);
            qstates[((size_t)(b * NH + h) * S_LEN + s) * 128 + 96 + j] = f2bf(val * QSCALE);
          }
        }
      }
    }
  } else if (n0 < 512) {  // ---- kv k_nope epilogue (r8-exact) ----
#pragma unroll
    for (int im = 0; im < 4; ++im)
#pragma unroll
      for (int in = 0; in < 4; ++in)
#pragma unroll
        for (int r = 0; r < 4; ++r) {
          int row = m0 + mw + im * 16 + quad * 4 + r;
          int col = n0 + nw + in * 16 + lane15;
          kvb[(size_t)row * 2560 + col] = f2bf(acc[im][in][r] + biaskv[col]);
        }
  } else {  // ---- kv V epilogue: two-pass LDS-staged coalesced vT write (r8-exact) ----
    const int sbase = m0 & (S_LEN - 1), bq = m0 >> 11;
#pragma unroll
    for (int hh = 0; hh < 2; ++hh) {
#pragma unroll
      for (int im = 0; im < 4; ++im) {
        const int rrel = mw + im * 16 + quad * 4;  // block-relative s, 0..127
        const int bb = (rrel & 63) >> 2;
        const int a = (bb & 8) | (((bb >> 1) & 1) << 2) | ((bb & 1) << 1) | ((bb >> 2) & 1);
        const int prel = (rrel >> 6) * 64 + a * 4;
#pragma unroll
        for (int ii = 0; ii < 2; ++ii) {
          const int in = hh * 2 + ii;
          const int nl = nw + in * 16 + lane15;
          const int slot = (nl & 31) | ((nl & 64) >> 1);
          const float bv = biaskv[n0 + nl];
          ushort4 o;
          o.x = f2bf(acc[im][in][0] + bv);
          o.y = f2bf(acc[im][in][1] + bv);
          o.z = f2bf(acc[im][in][2] + bv);
          o.w = f2bf(acc[im][in][3] + bv);
          *(ushort4*)&eplds[slot * 136 + prel] = o;
        }
      }
      __syncthreads();
#pragma unroll
      for (int i = 0; i < 4; ++i) {
        int idx = i * 256 + tid;
        int slot = idx >> 4, c8 = (idx & 15) * 8;
        int nl = (slot & 31) + hh * 32 + ((slot & 32) << 1);
        int c2 = n0 + nl - 512;
        int hv = c2 >> 8, nn = c2 & 255;
        short8 v = *(const short8*)&eplds[slot * 136 + c8];
        *(short8*)&vT[((size_t)((bq * NH + hv) * 256 + nn)) * 2048 + sbase + c8] = v;
      }
      if (hh == 0) __syncthreads();
    }
  }
}

// ------- stage-A epilogue: rmsnorm(cq), rmsnorm(ckv), rope(k_rope), q-rope table -------
__global__ void k_stagea(const float* __restrict__ t0, const float* __restrict__ qnw,
                         const float* __restrict__ kvnw, const int* __restrict__ pos_ids,
                         u16* __restrict__ cq, u16* __restrict__ ckv,
                         u16* __restrict__ krope, float* __restrict__ qtab) {
  int r = blockIdx.x, tid = threadIdx.x;  // 128 threads
  const float* row = t0 + (size_t)r * 320;
  float a = row[tid];
  float b = row[128 + tid];
  float sa = a * a, sb = b * b;
#pragma unroll
  for (int d = 1; d < 64; d <<= 1) {
    sa += __shfl_xor(sa, d);
    sb += __shfl_xor(sb, d);
  }
  __shared__ float red[4];
  if ((tid & 63) == 0) { red[(tid >> 6) * 2] = sa; red[(tid >> 6) * 2 + 1] = sb; }
  __syncthreads();
  sa = red[0] + red[2];
  sb = red[1] + red[3];
  float ra = rsqrtf(sa * (1.0f / 128.0f) + 1e-8f);
  float rb = rsqrtf(sb * (1.0f / 128.0f) + 1e-8f);
  cq[(size_t)r * 128 + tid] = f2bf(qnw[tid] * a * ra);
  ckv[(size_t)r * 128 + tid] = f2bf(kvnw[tid] * b * rb);
  if (tid < 32) {
    float xe = row[256 + 2 * tid], xo = row[256 + 2 * tid + 1];
    float p = (float)pos_ids[r];
    float freq = exp2f(-(2.0f * tid / 64.0f) * L2_THETA);
    float ang = p * freq;
    float c = cosf(ang), s = sinf(ang);
    krope[(size_t)r * 64 + 2 * tid] = f2bf(xe * c - xo * s);
    krope[(size_t)r * 64 + 2 * tid + 1] = f2bf(xe * s + xo * c);
  } else if (tid < 48) {
    // q-rope table: bitwise-identical formula to the old k_stageb path
    int pr = tid - 32;
    float p = (float)pos_ids[r];
    float freq = exp2f(-(2.0f * pr / 32.0f) * L2_THETA);
    float ang = p * freq;
    qtab[((size_t)r * 16 + pr) * 2] = cosf(ang);
    qtab[((size_t)r * 16 + pr) * 2 + 1] = sinf(ang);
  }
}

// ---------------- flash attention: 2-phase double-buffered pipeline (r3-exact) ----------
// Best-known attn: 88.1-92us, reproduced 11x. All deviations regressed. Do not edit.
__global__ __launch_bounds__(512) void k_attn(const u16* __restrict__ qstates,
                                              const u16* __restrict__ kv,
                                              const u16* __restrict__ krope,
                                              const u16* __restrict__ vT,
                                              u16* __restrict__ attn_out) {
  const int pair = blockIdx.x;  // 0..15 (pair-major: XCD = pair%8)
  const int qblk = blockIdx.y;  // 0..15
  const int b = pair >> 3, h = pair & 7;
  const int tid = threadIdx.x;
  const int wave = tid >> 6, lane = tid & 63;
  const int lane15 = lane & 15, quad = lane >> 4;
  const int w4 = wave & 3, half = wave >> 2;

  __shared__ __align__(16) u16 Klds[2][64 * 128];   // 2 x 16 KB
  __shared__ __align__(16) u16 Vlds[2][256 * 64];   // 2 x 32 KB

  const int qrow0 = qblk * 128 + wave * 16;
  short8 qfrag[4];
  {
    const u16* qb = qstates + ((size_t)(b * NH + h) * S_LEN + qrow0 + lane15) * 128 + quad * 8;
#pragma unroll
    for (int c = 0; c < 4; ++c) qfrag[c] = *(const short8*)(qb + c * 32);
  }

  floatx4 o_acc[16];
#pragma unroll
  for (int g = 0; g < 16; ++g) o_acc[g] = (floatx4){0.f, 0.f, 0.f, 0.f};
  float m_i = -1e30f;
  float l_i = 0.f;  // per-lane PARTIAL row-sum; reduced at epilogue

  // ---- hoisted, ch-invariant LDS read offsets (u16 units) ----
  const int kbase = (quad * 16 + lane15) * 8;  // + (t*16+c*4)*128 (imm)
  int vo0[4], vo1[4];
#pragma unroll
  for (int ph = 0; ph < 4; ++ph) {
    int n = ph * 16 + lane15;
    int sw = (n ^ (n >> 3)) & 7;
    vo0[ph] = n * 64 + ((quad ^ sw) & 7) * 8;
    vo1[ph] = n * 64 + (((quad | 4) ^ sw) & 7) * 8;
  }

  // K staging (512 thr, 2 cp16/thread): row = w4*16+lane15, unit u = half*8 + 4j + quad.
  const u16* kp[2];
  int kstr[2];
  int kdst[2];
#pragma unroll
  for (int j = 0; j < 2; ++j) {
    int u = half * 8 + j * 4 + quad;
    const u16* base;
    int str;
    if (u < 8) { base = kv + h * 64 + u * 8; str = 2560; }
    else { base = krope + (u - 8) * 8; str = 64; }
    kp[j] = base + (size_t)(b * S_LEN + w4 * 16 + lane15) * str;
    kstr[j] = str;
    kdst[j] = (w4 * 256 + (half * 2 + j) * 64 + lane) * 8;
  }
  // V staging (512 thr, 4 cp16/thread): n = oi*64 + (tid>>3), slot = tid&7
  const int vn6 = tid >> 3, vsl = tid & 7;
  const u16* vp[4];
#pragma unroll
  for (int oi = 0; oi < 4; ++oi) {
    int n = oi * 64 + vn6;
    int u = vsl ^ ((n ^ (n >> 3)) & 7);
    vp[oi] = vT + ((size_t)pair * 256 + n) * 2048 + u * 8;
  }

  auto issueK = [&](int buf) {
#pragma unroll
    for (int j = 0; j < 2; ++j) {
      cp16(kp[j], &Klds[buf][kdst[j]]);
      kp[j] += (size_t)64 * kstr[j];
    }
  };
  auto issueV = [&](int buf) {
#pragma unroll
    for (int oi = 0; oi < 4; ++oi) {
      cp16(vp[oi], &Vlds[buf][(oi * 512 + tid) * 8]);
      vp[oi] += 64;
    }
  };

  // prologue: fill buf0, drain, converge
  issueK(0);
  issueV(0);
  asm volatile("s_waitcnt vmcnt(0)" ::: "memory");
  __builtin_amdgcn_sched_barrier(0);
  __builtin_amdgcn_s_barrier();

  int cur = 0;
  for (int ch = 0; ch < S_LEN / 64; ++ch) {
    if (ch + 1 < S_LEN / 64) {
      issueK(cur ^ 1);
      issueV(cur ^ 1);
    }

    // S^T = K * Q^T : st[t][r] = S[q=lane15][k = t*16 + quad*4 + r] (log2 domain)
    floatx4 st[4];
#pragma unroll
    for (int t = 0; t < 4; ++t) st[t] = (floatx4){0.f, 0.f, 0.f, 0.f};
    __builtin_amdgcn_s_setprio(1);
#pragma unroll
    for (int c = 0; c < 4; ++c) {
      short8 qf = qfrag[c];
#pragma unroll
      for (int t = 0; t < 4; ++t) {
        short8 kf = *(const short8*)&Klds[cur][kbase + (t * 16 + c * 4) * 128];
        st[t] = mfma16(kf, qf, st[t]);
      }
    }
    __builtin_amdgcn_s_setprio(0);

    // row max: fmax tree + 2-shfl butterfly (l-sum reduce deferred to epilogue)
    float mloc = st[0][0];
#pragma unroll
    for (int t = 0; t < 4; ++t)
#pragma unroll
      for (int r = 0; r < 4; ++r) mloc = fmaxf(mloc, st[t][r]);
    mloc = fmaxf(mloc, __shfl_xor(mloc, 16));
    mloc = fmaxf(mloc, __shfl_xor(mloc, 32));

    // defer-max: only rescale when max grew by >8 (log2 domain); P bounded by 2^8
    const bool resc = __any(mloc > m_i + 8.0f);
    const float mref = resc ? fmaxf(m_i, mloc) : m_i;

    float rs = 0.f;
    union { short8 s; uint4 u; } a01, a23;
    {
      float p0, p1, p2, p3;
      p0 = exp2f(st[0][0] - mref); p1 = exp2f(st[0][1] - mref);
      p2 = exp2f(st[0][2] - mref); p3 = exp2f(st[0][3] - mref);
      rs += (p0 + p1) + (p2 + p3);
      a01.u.x = pkbf(p0, p1); a01.u.y = pkbf(p2, p3);
      p0 = exp2f(st[1][0] - mref); p1 = exp2f(st[1][1] - mref);
      p2 = exp2f(st[1][2] - mref); p3 = exp2f(st[1][3] - mref);
      rs += (p0 + p1) + (p2 + p3);
      a01.u.z = pkbf(p0, p1); a01.u.w = pkbf(p2, p3);
      p0 = exp2f(st[2][0] - mref); p1 = exp2f(st[2][1] - mref);
      p2 = exp2f(st[2][2] - mref); p3 = exp2f(st[2][3] - mref);
      rs += (p0 + p1) + (p2 + p3);
      a23.u.x = pkbf(p0, p1); a23.u.y = pkbf(p2, p3);
      p0 = exp2f(st[3][0] - mref); p1 = exp2f(st[3][1] - mref);
      p2 = exp2f(st[3][2] - mref); p3 = exp2f(st[3][3] - mref);
      rs += (p0 + p1) + (p2 + p3);
      a23.u.z = pkbf(p0, p1); a23.u.w = pkbf(p2, p3);
    }

    if (resc) {  // rare after chunk 0 (THR=8): alpha rescale of o_acc + l_i
      float alpha = exp2f(m_i - mref);
      m_i = mref;
      l_i = l_i * alpha + rs;
      float al[4];
#pragma unroll
      for (int r = 0; r < 4; ++r) al[r] = __shfl(alpha, quad * 4 + r, 16);
#pragma unroll
      for (int g = 0; g < 16; ++g) {
        o_acc[g][0] *= al[0]; o_acc[g][1] *= al[1];
        o_acc[g][2] *= al[2]; o_acc[g][3] *= al[3];
      }
    } else {
      l_i += rs;
    }

    // PV: b-frags are single b128 reads (permuted-k vT layout, hoisted bases)
    __builtin_amdgcn_s_setprio(1);
#pragma unroll
    for (int g = 0; g < 16; ++g) {
      short8 b01 = *(const short8*)&Vlds[cur][vo0[g & 3] + (g >> 2) * 4096];
      short8 b23 = *(const short8*)&Vlds[cur][vo1[g & 3] + (g >> 2) * 4096];
      floatx4 o = o_acc[g];
      o = mfma16(a01.s, b01, o);
      o = mfma16(a23.s, b23, o);
      o_acc[g] = o;
    }
    __builtin_amdgcn_s_setprio(0);

    // single per-chunk sync: next-chunk loads had all of compute to land;
    // barrier seals this chunk's LDS reads before buf[cur] is overwritten.
    asm volatile("s_waitcnt vmcnt(0)" ::: "memory");
    __builtin_amdgcn_sched_barrier(0);
    __builtin_amdgcn_s_barrier();
    cur ^= 1;
  }

  // epilogue: reduce the per-quad partial row-sums once, then normalize
  float lsum = l_i;
  lsum += __shfl_xor(lsum, 16);
  lsum += __shfl_xor(lsum, 32);
  float rl = 1.0f / lsum;
  float linv[4];
#pragma unroll
  for (int r = 0; r < 4; ++r) linv[r] = __shfl(rl, quad * 4 + r, 16);
#pragma unroll
  for (int g = 0; g < 16; ++g) {
#pragma unroll
    for (int r = 0; r < 4; ++r) {
      int row = qrow0 + quad * 4 + r;
      int col = h * 256 + g * 16 + lane15;
      attn_out[((size_t)b * S_LEN + row) * 2048 + col] = f2bf(o_acc[g][r] * linv[r]);
    }
  }
}

extern "C" void kernel_launch(void* const* d_in, const int* in_sizes, int n_in,
                              void* d_out, int out_size, void* d_ws, size_t ws_size,
                              hipStream_t stream) {
  const float* x = (const float*)d_in[0];
  const int* pos = (const int*)d_in[1];
  const float* wdq = (const float*)d_in[2];
  const float* bdq = (const float*)d_in[3];
  const float* qnw = (const float*)d_in[4];
  const float* wuq = (const float*)d_in[5];
  const float* buq = (const float*)d_in[6];
  const float* wdkv = (const float*)d_in[7];
  const float* bdkv = (const float*)d_in[8];
  const float* kvnw = (const float*)d_in[9];
  const float* wukv = (const float*)d_in[10];
  const float* bukv = (const float*)d_in[11];
  const float* wo = (const float*)d_in[12];
  const float* bo = (const float*)d_in[13];
  float* out = (float*)d_out;

  char* ws = (char*)d_ws;
  size_t off = 0;
  auto alloc = [&](size_t bytes) {
    char* p = ws + off;
    off += (bytes + 255) & ~(size_t)255;
    return p;
  };
  // vT (16.78MB) aliases xbf+t0+qout_spacer (22MB): all dead before k_gemm_qkv runs.
  // qout is no longer written (stageb fused) but KEPT as a spacer so the alias hole
  // stays >= vT size (removing it would shift wKVT into vT's range).
  u16* xbf = (u16*)alloc((size_t)R_TOK * 1024 * 2);    // dead after gemm A
  float* t0 = (float*)alloc((size_t)R_TOK * 320 * 4);  // dead after stagea
  u16* qout = (u16*)alloc((size_t)R_TOK * 1024 * 2);   // UNUSED spacer (alias hole)
  u16* vT = (u16*)d_ws;                                // alias of the three above
  u16* waT = (u16*)alloc((size_t)384 * 1024 * 2);      // padded 320->384 rows
  float* biasA = (float*)alloc(320 * 4);
  u16* wQT = (u16*)alloc((size_t)1024 * 128 * 2);
  u16* wKVT = (u16*)alloc((size_t)2560 * 128 * 2);
  u16* wOT = (u16*)alloc((size_t)1024 * 2048 * 2);
  u16* cq = (u16*)alloc((size_t)R_TOK * 128 * 2);
  u16* ckv = (u16*)alloc((size_t)R_TOK * 128 * 2);
  u16* krope = (u16*)alloc((size_t)R_TOK * 64 * 2);
  u16* qst = (u16*)alloc((size_t)R_TOK * 1024 * 2);
  u16* kvb = (u16*)alloc((size_t)R_TOK * 2560 * 2);
  u16* attnb = (u16*)alloc((size_t)R_TOK * 2048 * 2);
  float* qtab = (float*)alloc((size_t)R_TOK * 16 * 2 * 4);  // q-rope cos/sin table, 512KB
  (void)ws_size; (void)n_in; (void)in_sizes; (void)out_size; (void)qout;

  // prep part 1: x->bf16, waT, biasA (r12-exact)
  k_prep1<<<4417, 256, 0, stream>>>(x, xbf, wdq, wdkv, waT, bdq, bdkv, biasA);
  // gemm-A (192 blocks, 64x128 tile, BK=64) + weight transposes (2496 blocks)
  k_gemma_wt<<<2688, 256, 0, stream>>>(xbf, waT, biasA, t0,
                                       wuq, wQT, wukv, wKVT, wo, wOT);
  k_stagea<<<R_TOK, 128, 0, stream>>>(t0, qnw, kvnw, pos, cq, ckv, krope, qtab);
  // fused q + kv up-projections (independent): 256 q-blocks + 640 kv-blocks, one launch
  k_gemm_qkv<<<896, 256, 0, stream>>>(cq, wQT, buq, qtab, qst, ckv, wKVT, bukv, kvb, vT);
  // attention: 256 blocks (1/CU, 96KB LDS, 8 waves = 2/SIMD), 512 threads (r3-exact)
  k_attn<<<dim3(16, 16), 512, 0, stream>>>(qst, kvb, krope, vT, attnb);
  // output projection -> fp32 out: 64x128 tile, BK=64, 512 blocks = 2/CU
  k_gemm_o<<<dim3(8, 64), 256, 0, stream>>>(attnb, wOT, bo, out);
}